// Round 1
// baseline (1894.221 us; speedup 1.0000x reference)
//
#include <hip/hip_runtime.h>

#define NN 50000
#define NE 640000
#define BNEPS 1e-5f

// ---------------- small kernels ----------------
__global__ __launch_bounds__(256) void init_k(float* __restrict__ deg,
                                              float* __restrict__ stats) {
  int i = blockIdx.x * 256 + threadIdx.x;
  if (i < NN) deg[i] = 1.0f;      // self loop
  if (i < 1024) stats[i] = 0.0f;  // zero BN stat accumulators
}

__global__ __launch_bounds__(256) void deg_k(const int* __restrict__ dst,
                                             float* __restrict__ deg) {
  int e = blockIdx.x * 256 + threadIdx.x;
  if (e < NE) atomicAdd(&deg[dst[e]], 1.0f);
}

__global__ __launch_bounds__(256) void dinv_k(float* __restrict__ deg) {
  int i = blockIdx.x * 256 + threadIdx.x;
  if (i < NN) deg[i] = rsqrtf(deg[i]);  // deg >= 1 always
}

// ---------------- BN stats ----------------
// MODE 0: v = A[r][c]          MODE 1: v = A[r][c]*dinv[r] + cb[c]
template <int NC, int MODE>
__global__ __launch_bounds__(256) void bn_stats_k(const float* __restrict__ A,
                                                  const float* __restrict__ dinv,
                                                  const float* __restrict__ cb,
                                                  float* __restrict__ sums,
                                                  float* __restrict__ sqs) {
  constexpr int CG = NC / 4;
  constexpr int RG = 256 / CG;
  const int tc = threadIdx.x % CG;
  const int tr = threadIdx.x / CG;
  float cb0 = 0, cb1 = 0, cb2 = 0, cb3 = 0;
  if (MODE == 1) {
    cb0 = cb[tc * 4];
    cb1 = cb[tc * 4 + 1];
    cb2 = cb[tc * 4 + 2];
    cb3 = cb[tc * 4 + 3];
  }
  float s0 = 0, s1 = 0, s2 = 0, s3 = 0, q0 = 0, q1 = 0, q2 = 0, q3 = 0;
  for (int r = blockIdx.x * RG + tr; r < NN; r += gridDim.x * RG) {
    float4 v = *(const float4*)&A[(size_t)r * NC + tc * 4];
    if (MODE == 1) {
      float di = dinv[r];
      v.x = fmaf(v.x, di, cb0);
      v.y = fmaf(v.y, di, cb1);
      v.z = fmaf(v.z, di, cb2);
      v.w = fmaf(v.w, di, cb3);
    }
    s0 += v.x; s1 += v.y; s2 += v.z; s3 += v.w;
    q0 += v.x * v.x; q1 += v.y * v.y; q2 += v.z * v.z; q3 += v.w * v.w;
  }
  __shared__ float rs[RG][NC];
  __shared__ float rq[RG][NC];
  rs[tr][tc * 4] = s0; rs[tr][tc * 4 + 1] = s1;
  rs[tr][tc * 4 + 2] = s2; rs[tr][tc * 4 + 3] = s3;
  rq[tr][tc * 4] = q0; rq[tr][tc * 4 + 1] = q1;
  rq[tr][tc * 4 + 2] = q2; rq[tr][tc * 4 + 3] = q3;
  __syncthreads();
  if (tr == 0) {
    for (int j = 0; j < 4; ++j) {
      int c = tc * 4 + j;
      float ts = 0, tq = 0;
      for (int g = 0; g < RG; ++g) { ts += rs[g][c]; tq += rq[g][c]; }
      atomicAdd(&sums[c], ts);
      atomicAdd(&sqs[c], tq);
    }
  }
}

__global__ void bn_finalize_k(const float* __restrict__ sums,
                              const float* __restrict__ sqs,
                              const float* __restrict__ gamma,
                              const float* __restrict__ beta,
                              float* __restrict__ af, float* __restrict__ bf,
                              int nc) {
  int c = threadIdx.x;
  if (c < nc) {
    float m = sums[c] * (1.0f / NN);
    float v = sqs[c] * (1.0f / NN) - m * m;
    float a = gamma[c] * rsqrtf(v + BNEPS);
    af[c] = a;
    bf[c] = beta[c] - m * a;
  }
}

// ---------------- fused GEMM ----------------
// C[row][col] = sum_k pre(A[row][k]) * W[k][col], K = 128 fixed.
// PRE: 0 = af[k]*v+bf[k] ; 1 = v ; 2 = relu(af[k]*(dinv[row]*v+preb[k])+bf[k])
// EPI: 0 = relu(acc + bias[c]) -> O1 ; 1 = acc*dinv[row] -> O1 and O2
template <int NC, int NT, int PRE, int EPI>
__global__ __launch_bounds__(NT) void gemm_fused_k(
    const float* __restrict__ A, const float* __restrict__ W,
    const float* __restrict__ bias, const float* __restrict__ af,
    const float* __restrict__ bf, const float* __restrict__ preb,
    const float* __restrict__ dinv, float* __restrict__ O1,
    float* __restrict__ O2) {
  constexpr int CG = NC / 4;    // col groups of 4
  constexpr int RG = NT / CG;   // row-thread groups
  constexpr int TR = RG * 8;    // tile rows (= 64)
  constexpr int ATS = TR + 4;   // padded stride (68): 16B aligned, no bank conflict
  constexpr int KC = 32;
  __shared__ float AT[128 * ATS];
  __shared__ float Wch[KC * NC];

  const int tid = threadIdx.x;
  const int tc = tid % CG;
  const int tr = tid / CG;
  const int row0 = blockIdx.x * TR;

  // stage A^T with pre-op applied
  for (int f = tid; f < TR * 32; f += NT) {
    const int r = f >> 5;
    const int c4 = f & 31;
    const int rg = row0 + r;
    float4 v = make_float4(0.f, 0.f, 0.f, 0.f);
    if (rg < NN) {
      v = *(const float4*)&A[(size_t)rg * 128 + c4 * 4];
      if (PRE == 0) {
        const float4 a4 = *(const float4*)&af[c4 * 4];
        const float4 b4 = *(const float4*)&bf[c4 * 4];
        v.x = fmaf(a4.x, v.x, b4.x);
        v.y = fmaf(a4.y, v.y, b4.y);
        v.z = fmaf(a4.z, v.z, b4.z);
        v.w = fmaf(a4.w, v.w, b4.w);
      } else if (PRE == 2) {
        const float di = dinv[rg];
        const float4 a4 = *(const float4*)&af[c4 * 4];
        const float4 b4 = *(const float4*)&bf[c4 * 4];
        const float4 p4 = *(const float4*)&preb[c4 * 4];
        v.x = fmaxf(fmaf(a4.x, fmaf(di, v.x, p4.x), b4.x), 0.f);
        v.y = fmaxf(fmaf(a4.y, fmaf(di, v.y, p4.y), b4.y), 0.f);
        v.z = fmaxf(fmaf(a4.z, fmaf(di, v.z, p4.z), b4.z), 0.f);
        v.w = fmaxf(fmaf(a4.w, fmaf(di, v.w, p4.w), b4.w), 0.f);
      }
    }
    const int k = c4 * 4;
    AT[(k + 0) * ATS + r] = v.x;
    AT[(k + 1) * ATS + r] = v.y;
    AT[(k + 2) * ATS + r] = v.z;
    AT[(k + 3) * ATS + r] = v.w;
  }

  float acc[8][4];
#pragma unroll
  for (int i = 0; i < 8; ++i)
#pragma unroll
    for (int j = 0; j < 4; ++j) acc[i][j] = 0.f;

  for (int kc = 0; kc < 128 / KC; ++kc) {
    __syncthreads();
    for (int f = tid; f < KC * CG; f += NT) {
      const int k = f / CG;
      const int c4 = f % CG;
      *(float4*)&Wch[k * NC + c4 * 4] =
          *(const float4*)&W[(size_t)(kc * KC + k) * NC + c4 * 4];
    }
    __syncthreads();
#pragma unroll
    for (int k = 0; k < KC; ++k) {
      const float4 b = *(const float4*)&Wch[k * NC + tc * 4];
      const float4 a0 = *(const float4*)&AT[(kc * KC + k) * ATS + tr * 8];
      const float4 a1 = *(const float4*)&AT[(kc * KC + k) * ATS + tr * 8 + 4];
      const float av[8] = {a0.x, a0.y, a0.z, a0.w, a1.x, a1.y, a1.z, a1.w};
#pragma unroll
      for (int i = 0; i < 8; ++i) {
        acc[i][0] = fmaf(av[i], b.x, acc[i][0]);
        acc[i][1] = fmaf(av[i], b.y, acc[i][1]);
        acc[i][2] = fmaf(av[i], b.z, acc[i][2]);
        acc[i][3] = fmaf(av[i], b.w, acc[i][3]);
      }
    }
  }

  float4 b4 = make_float4(0.f, 0.f, 0.f, 0.f);
  if (EPI == 0) b4 = *(const float4*)&bias[tc * 4];
#pragma unroll
  for (int i = 0; i < 8; ++i) {
    const int rg = row0 + tr * 8 + i;
    if (rg < NN) {
      float4 o;
      if (EPI == 0) {
        o.x = fmaxf(acc[i][0] + b4.x, 0.f);
        o.y = fmaxf(acc[i][1] + b4.y, 0.f);
        o.z = fmaxf(acc[i][2] + b4.z, 0.f);
        o.w = fmaxf(acc[i][3] + b4.w, 0.f);
        *(float4*)&O1[(size_t)rg * NC + tc * 4] = o;
      } else {
        const float s = dinv[rg];
        o.x = acc[i][0] * s;
        o.y = acc[i][1] * s;
        o.z = acc[i][2] * s;
        o.w = acc[i][3] * s;
        *(float4*)&O1[(size_t)rg * NC + tc * 4] = o;
        *(float4*)&O2[(size_t)rg * NC + tc * 4] = o;
      }
    }
  }
}

// ---------------- edge scatter ----------------
template <int NC>
__global__ __launch_bounds__(256) void scatter_k(const int* __restrict__ src,
                                                 const int* __restrict__ dst,
                                                 const float* __restrict__ Y,
                                                 float* __restrict__ ACC) {
  constexpr int CG = NC / 4;
  const int u = blockIdx.x * 256 + threadIdx.x;
  const int e = u / CG;
  if (e >= NE) return;
  const int c = (u % CG) * 4;
  const int s = src[e];
  const int d = dst[e];
  const float4 y = *(const float4*)&Y[(size_t)s * NC + c];
  float* p = &ACC[(size_t)d * NC + c];
  atomicAdd(p + 0, y.x);
  atomicAdd(p + 1, y.y);
  atomicAdd(p + 2, y.z);
  atomicAdd(p + 3, y.w);
}

// ---------------- final BN apply ----------------
__global__ __launch_bounds__(256) void final_k(const float* __restrict__ ACC2,
                                               const float* __restrict__ dinv,
                                               const float* __restrict__ cb,
                                               const float* __restrict__ af,
                                               const float* __restrict__ bf,
                                               float* __restrict__ out) {
  const int u = blockIdx.x * 256 + threadIdx.x;
  if (u >= NN * 16) return;
  const int r = u >> 4;
  const int c = (u & 15) * 4;
  const float di = dinv[r];
  float4 v = *(const float4*)&ACC2[(size_t)r * 64 + c];
  const float4 c4 = *(const float4*)&cb[c];
  const float4 a4 = *(const float4*)&af[c];
  const float4 b4 = *(const float4*)&bf[c];
  float4 o;
  o.x = fmaf(a4.x, fmaf(v.x, di, c4.x), b4.x);
  o.y = fmaf(a4.y, fmaf(v.y, di, c4.y), b4.y);
  o.z = fmaf(a4.z, fmaf(v.z, di, c4.z), b4.z);
  o.w = fmaf(a4.w, fmaf(v.w, di, c4.w), b4.w);
  *(float4*)&out[(size_t)r * 64 + c] = o;
}

extern "C" void kernel_launch(void* const* d_in, const int* in_sizes, int n_in,
                              void* d_out, int out_size, void* d_ws,
                              size_t ws_size, hipStream_t stream) {
  const float* x = (const float*)d_in[0];
  const int* ei = (const int*)d_in[1];
  const int* src = ei;
  const int* dst = ei + NE;
  const float* bn_in_g = (const float*)d_in[2];
  const float* bn_in_b = (const float*)d_in[3];
  const float* bn1_g = (const float*)d_in[4];
  const float* bn1_b = (const float*)d_in[5];
  const float* bn2_g = (const float*)d_in[6];
  const float* bn2_b = (const float*)d_in[7];
  const float* proj_W = (const float*)d_in[8];
  const float* proj_b = (const float*)d_in[9];
  const float* conv1_W = (const float*)d_in[10];
  const float* conv1_b = (const float*)d_in[11];
  const float* conv2_W = (const float*)d_in[12];
  const float* conv2_b = (const float*)d_in[13];
  float* out = (float*)d_out;

  float* ws = (float*)d_ws;
  float* dinv = ws;            // NN floats
  float* st = ws + 51200;      // stats + affine block
  float* s0 = st;              float* q0 = st + 128;
  float* s1 = st + 256;        float* q1 = st + 384;
  float* s2 = st + 512;        float* q2 = st + 576;
  float* af0 = st + 640;       float* bf0 = st + 768;
  float* af1 = st + 896;       float* bf1 = st + 1024;
  float* af2 = st + 1152;      float* bf2 = st + 1216;
  float* big = ws + 53248;
  float* H1 = big;                              // NN*128
  float* Y = big + (size_t)NN * 128;            // NN*128
  float* ACC = big + (size_t)NN * 128 * 2;      // NN*128
  float* Y2 = H1;                               // NN*64 (reuse)
  float* ACC2 = Y;                              // NN*64 (reuse)

  const int nb_n = (NN + 255) / 256;
  init_k<<<nb_n, 256, 0, stream>>>(dinv, st);
  deg_k<<<(NE + 255) / 256, 256, 0, stream>>>(dst, dinv);
  dinv_k<<<nb_n, 256, 0, stream>>>(dinv);

  // layer 0: BN(x) folded into GEMM1 staging
  bn_stats_k<128, 0><<<256, 256, 0, stream>>>(x, nullptr, nullptr, s0, q0);
  bn_finalize_k<<<1, 128, 0, stream>>>(s0, q0, bn_in_g, bn_in_b, af0, bf0, 128);

  const int nt64 = (NN + 63) / 64;  // 782 row tiles
  // H1 = relu(BN(x) @ proj_W + proj_b)
  gemm_fused_k<128, 256, 0, 0><<<nt64, 256, 0, stream>>>(
      x, proj_W, proj_b, af0, bf0, nullptr, dinv, H1, nullptr);
  // conv1: Y = (H1 @ conv1_W) * dinv[row]; ACC init = Y (self loop)
  gemm_fused_k<128, 256, 1, 1><<<nt64, 256, 0, stream>>>(
      H1, conv1_W, nullptr, nullptr, nullptr, nullptr, dinv, Y, ACC);
  scatter_k<128><<<(NE * 32 + 255) / 256, 256, 0, stream>>>(src, dst, Y, ACC);
  // BN1 stats on z1 = dinv[r]*ACC + conv1_b
  bn_stats_k<128, 1><<<256, 256, 0, stream>>>(ACC, dinv, conv1_b, s1, q1);
  bn_finalize_k<<<1, 128, 0, stream>>>(s1, q1, bn1_g, bn1_b, af1, bf1, 128);
  // conv2: input = relu(BN1(z1)) computed in staging; 64 output cols
  gemm_fused_k<64, 128, 2, 1><<<nt64, 128, 0, stream>>>(
      ACC, conv2_W, nullptr, af1, bf1, conv1_b, dinv, Y2, ACC2);
  scatter_k<64><<<(NE * 16 + 255) / 256, 256, 0, stream>>>(src, dst, Y2, ACC2);
  // BN2 stats on z2 = dinv[r]*ACC2 + conv2_b
  bn_stats_k<64, 1><<<256, 256, 0, stream>>>(ACC2, dinv, conv2_b, s2, q2);
  bn_finalize_k<<<1, 128, 0, stream>>>(s2, q2, bn2_g, bn2_b, af2, bf2, 64);
  final_k<<<(NN * 16 + 255) / 256, 256, 0, stream>>>(ACC2, dinv, conv2_b, af2,
                                                     bf2, out);
}

// Round 6
// 507.928 us; speedup vs baseline: 3.7293x; 3.7293x over previous
//
#include <hip/hip_runtime.h>

#define NN 50000
#define NE 640000
#define BNEPS 1e-5f

// workspace layout (float offsets) — total 13,644,800 floats = 54.6 MB
#define OFF_DINV 0
#define OFF_ST 51200
#define OFF_DEG 53248
#define OFF_ROWSTART 103424
#define OFF_CURSOR 153600
#define OFF_ESRC 203776
#define OFF_B0 844800
#define OFF_B1 7244800

// ---------------- small kernels ----------------
__global__ __launch_bounds__(256) void init_k(int* __restrict__ deg,
                                              float* __restrict__ stats) {
  int i = blockIdx.x * 256 + threadIdx.x;
  if (i < NN) deg[i] = 0;
  if (i < 1024) stats[i] = 0.0f;  // zero BN stat accumulators
}

__global__ __launch_bounds__(256) void deg_k(const int* __restrict__ dst,
                                             int* __restrict__ deg) {
  int e = blockIdx.x * 256 + threadIdx.x;
  if (e < NE) atomicAdd(&deg[dst[e]], 1);
}

// single-block exclusive scan over deg -> rowstart/cursor; rowstart[NN]=NE
__global__ __launch_bounds__(1024) void scan_k(const int* __restrict__ deg,
                                               int* __restrict__ rowstart,
                                               int* __restrict__ cursor,
                                               float* __restrict__ dinv) {
  constexpr int CH = (NN + 1023) / 1024;  // 49
  const int t = threadIdx.x;
  const int beg = t * CH;
  const int end = (beg + CH < NN) ? beg + CH : NN;
  int s = 0;
  for (int i = beg; i < end; ++i) s += deg[i];
  __shared__ int ps[1024];
  ps[t] = s;
  __syncthreads();
  // Hillis-Steele inclusive scan
  for (int off = 1; off < 1024; off <<= 1) {
    int v = (t >= off) ? ps[t - off] : 0;
    __syncthreads();
    ps[t] += v;
    __syncthreads();
  }
  int run = ps[t] - s;  // exclusive
  for (int i = beg; i < end; ++i) {
    rowstart[i] = run;
    cursor[i] = run;
    run += deg[i];
    dinv[i] = rsqrtf((float)deg[i] + 1.0f);  // +1 self loop
  }
  if (t == 1023) rowstart[NN] = NE;
}

__global__ __launch_bounds__(256) void fill_k(const int* __restrict__ src,
                                              const int* __restrict__ dst,
                                              int* __restrict__ cursor,
                                              int* __restrict__ esrc) {
  int e = blockIdx.x * 256 + threadIdx.x;
  if (e < NE) {
    int p = atomicAdd(&cursor[dst[e]], 1);
    esrc[p] = src[e];
  }
}

// ---------------- BN stats ----------------
// MODE 0: v = A[r][c]          MODE 1: v = A[r][c]*dinv[r] + cb[c]
template <int NC, int MODE>
__global__ __launch_bounds__(256) void bn_stats_k(const float* __restrict__ A,
                                                  const float* __restrict__ dinv,
                                                  const float* __restrict__ cb,
                                                  float* __restrict__ sums,
                                                  float* __restrict__ sqs) {
  constexpr int CG = NC / 4;
  constexpr int RG = 256 / CG;
  const int tc = threadIdx.x % CG;
  const int tr = threadIdx.x / CG;
  float cb0 = 0, cb1 = 0, cb2 = 0, cb3 = 0;
  if (MODE == 1) {
    cb0 = cb[tc * 4];
    cb1 = cb[tc * 4 + 1];
    cb2 = cb[tc * 4 + 2];
    cb3 = cb[tc * 4 + 3];
  }
  float s0 = 0, s1 = 0, s2 = 0, s3 = 0, q0 = 0, q1 = 0, q2 = 0, q3 = 0;
  for (int r = blockIdx.x * RG + tr; r < NN; r += gridDim.x * RG) {
    float4 v = *(const float4*)&A[(size_t)r * NC + tc * 4];
    if (MODE == 1) {
      float di = dinv[r];
      v.x = fmaf(v.x, di, cb0);
      v.y = fmaf(v.y, di, cb1);
      v.z = fmaf(v.z, di, cb2);
      v.w = fmaf(v.w, di, cb3);
    }
    s0 += v.x; s1 += v.y; s2 += v.z; s3 += v.w;
    q0 += v.x * v.x; q1 += v.y * v.y; q2 += v.z * v.z; q3 += v.w * v.w;
  }
  __shared__ float rs[RG][NC];
  __shared__ float rq[RG][NC];
  rs[tr][tc * 4] = s0; rs[tr][tc * 4 + 1] = s1;
  rs[tr][tc * 4 + 2] = s2; rs[tr][tc * 4 + 3] = s3;
  rq[tr][tc * 4] = q0; rq[tr][tc * 4 + 1] = q1;
  rq[tr][tc * 4 + 2] = q2; rq[tr][tc * 4 + 3] = q3;
  __syncthreads();
  if (tr == 0) {
    for (int j = 0; j < 4; ++j) {
      int c = tc * 4 + j;
      float ts = 0, tq = 0;
      for (int g = 0; g < RG; ++g) { ts += rs[g][c]; tq += rq[g][c]; }
      atomicAdd(&sums[c], ts);
      atomicAdd(&sqs[c], tq);
    }
  }
}

__global__ void bn_finalize_k(const float* __restrict__ sums,
                              const float* __restrict__ sqs,
                              const float* __restrict__ gamma,
                              const float* __restrict__ beta,
                              float* __restrict__ af, float* __restrict__ bf,
                              int nc) {
  int c = threadIdx.x;
  if (c < nc) {
    float m = sums[c] * (1.0f / NN);
    float v = sqs[c] * (1.0f / NN) - m * m;
    float a = gamma[c] * rsqrtf(v + BNEPS);
    af[c] = a;
    bf[c] = beta[c] - m * a;
  }
}

// ---------------- fused GEMM ----------------
// C[row][col] = sum_k pre(A[row][k]) * W[k][col], K = 128 fixed.
// PRE: 0 = af[k]*v+bf[k] ; 1 = v ; 2 = relu(af[k]*(dinv[row]*v+preb[k])+bf[k])
// EPI: 0 = relu(acc + bias[c]) ; 1 = acc*dinv[row]
template <int NC, int NT, int PRE, int EPI>
__global__ __launch_bounds__(NT) void gemm_fused_k(
    const float* __restrict__ A, const float* __restrict__ W,
    const float* __restrict__ bias, const float* __restrict__ af,
    const float* __restrict__ bf, const float* __restrict__ preb,
    const float* __restrict__ dinv, float* __restrict__ O1) {
  constexpr int CG = NC / 4;    // col groups of 4
  constexpr int RG = NT / CG;   // row-thread groups
  constexpr int TR = RG * 8;    // tile rows (= 64)
  constexpr int ATS = TR + 4;   // padded stride: 16B aligned, no bank conflict
  constexpr int KC = 32;
  __shared__ float AT[128 * ATS];
  __shared__ float Wch[KC * NC];

  const int tid = threadIdx.x;
  const int tc = tid % CG;
  const int tr = tid / CG;
  const int row0 = blockIdx.x * TR;

  // stage A^T with pre-op applied
  for (int f = tid; f < TR * 32; f += NT) {
    const int r = f >> 5;
    const int c4 = f & 31;
    const int rg = row0 + r;
    float4 v = make_float4(0.f, 0.f, 0.f, 0.f);
    if (rg < NN) {
      v = *(const float4*)&A[(size_t)rg * 128 + c4 * 4];
      if (PRE == 0) {
        const float4 a4 = *(const float4*)&af[c4 * 4];
        const float4 b4 = *(const float4*)&bf[c4 * 4];
        v.x = fmaf(a4.x, v.x, b4.x);
        v.y = fmaf(a4.y, v.y, b4.y);
        v.z = fmaf(a4.z, v.z, b4.z);
        v.w = fmaf(a4.w, v.w, b4.w);
      } else if (PRE == 2) {
        const float di = dinv[rg];
        const float4 a4 = *(const float4*)&af[c4 * 4];
        const float4 b4 = *(const float4*)&bf[c4 * 4];
        const float4 p4 = *(const float4*)&preb[c4 * 4];
        v.x = fmaxf(fmaf(a4.x, fmaf(di, v.x, p4.x), b4.x), 0.f);
        v.y = fmaxf(fmaf(a4.y, fmaf(di, v.y, p4.y), b4.y), 0.f);
        v.z = fmaxf(fmaf(a4.z, fmaf(di, v.z, p4.z), b4.z), 0.f);
        v.w = fmaxf(fmaf(a4.w, fmaf(di, v.w, p4.w), b4.w), 0.f);
      }
    }
    const int k = c4 * 4;
    AT[(k + 0) * ATS + r] = v.x;
    AT[(k + 1) * ATS + r] = v.y;
    AT[(k + 2) * ATS + r] = v.z;
    AT[(k + 3) * ATS + r] = v.w;
  }

  float acc[8][4];
#pragma unroll
  for (int i = 0; i < 8; ++i)
#pragma unroll
    for (int j = 0; j < 4; ++j) acc[i][j] = 0.f;

  for (int kc = 0; kc < 128 / KC; ++kc) {
    __syncthreads();
    for (int f = tid; f < KC * CG; f += NT) {
      const int k = f / CG;
      const int c4 = f % CG;
      *(float4*)&Wch[k * NC + c4 * 4] =
          *(const float4*)&W[(size_t)(kc * KC + k) * NC + c4 * 4];
    }
    __syncthreads();
#pragma unroll
    for (int k = 0; k < KC; ++k) {
      const float4 b = *(const float4*)&Wch[k * NC + tc * 4];
      const float4 a0 = *(const float4*)&AT[(kc * KC + k) * ATS + tr * 8];
      const float4 a1 = *(const float4*)&AT[(kc * KC + k) * ATS + tr * 8 + 4];
      const float av[8] = {a0.x, a0.y, a0.z, a0.w, a1.x, a1.y, a1.z, a1.w};
#pragma unroll
      for (int i = 0; i < 8; ++i) {
        acc[i][0] = fmaf(av[i], b.x, acc[i][0]);
        acc[i][1] = fmaf(av[i], b.y, acc[i][1]);
        acc[i][2] = fmaf(av[i], b.z, acc[i][2]);
        acc[i][3] = fmaf(av[i], b.w, acc[i][3]);
      }
    }
  }

  float4 b4 = make_float4(0.f, 0.f, 0.f, 0.f);
  if (EPI == 0) b4 = *(const float4*)&bias[tc * 4];
#pragma unroll
  for (int i = 0; i < 8; ++i) {
    const int rg = row0 + tr * 8 + i;
    if (rg < NN) {
      float4 o;
      if (EPI == 0) {
        o.x = fmaxf(acc[i][0] + b4.x, 0.f);
        o.y = fmaxf(acc[i][1] + b4.y, 0.f);
        o.z = fmaxf(acc[i][2] + b4.z, 0.f);
        o.w = fmaxf(acc[i][3] + b4.w, 0.f);
      } else {
        const float s = dinv[rg];
        o.x = acc[i][0] * s;
        o.y = acc[i][1] * s;
        o.z = acc[i][2] * s;
        o.w = acc[i][3] * s;
      }
      *(float4*)&O1[(size_t)rg * NC + tc * 4] = o;
    }
  }
}

// ---------------- CSR gather aggregation ----------------
// ACC[d] = Y[d] (self loop) + sum_{e in in(d)} Y[esrc[e]]
template <int NC>
__global__ __launch_bounds__(256) void gather_k(const int* __restrict__ rowstart,
                                                const int* __restrict__ esrc,
                                                const float* __restrict__ Y,
                                                float* __restrict__ ACC) {
  constexpr int CG = NC / 4;
  constexpr int RG = 256 / CG;
  const int tc = threadIdx.x % CG;
  const int tr = threadIdx.x / CG;
  const int n = blockIdx.x * RG + tr;
  if (n >= NN) return;
  const int c = tc * 4;
  float4 acc = *(const float4*)&Y[(size_t)n * NC + c];
  const int beg = rowstart[n];
  const int end = rowstart[n + 1];
  for (int e = beg; e < end; ++e) {
    const int s = esrc[e];
    const float4 y = *(const float4*)&Y[(size_t)s * NC + c];
    acc.x += y.x; acc.y += y.y; acc.z += y.z; acc.w += y.w;
  }
  *(float4*)&ACC[(size_t)n * NC + c] = acc;
}

// ---------------- final BN apply ----------------
__global__ __launch_bounds__(256) void final_k(const float* __restrict__ ACC2,
                                               const float* __restrict__ dinv,
                                               const float* __restrict__ cb,
                                               const float* __restrict__ af,
                                               const float* __restrict__ bf,
                                               float* __restrict__ out) {
  const int u = blockIdx.x * 256 + threadIdx.x;
  if (u >= NN * 16) return;
  const int r = u >> 4;
  const int c = (u & 15) * 4;
  const float di = dinv[r];
  float4 v = *(const float4*)&ACC2[(size_t)r * 64 + c];
  const float4 c4 = *(const float4*)&cb[c];
  const float4 a4 = *(const float4*)&af[c];
  const float4 b4 = *(const float4*)&bf[c];
  float4 o;
  o.x = fmaf(a4.x, fmaf(v.x, di, c4.x), b4.x);
  o.y = fmaf(a4.y, fmaf(v.y, di, c4.y), b4.y);
  o.z = fmaf(a4.z, fmaf(v.z, di, c4.z), b4.z);
  o.w = fmaf(a4.w, fmaf(v.w, di, c4.w), b4.w);
  *(float4*)&out[(size_t)r * 64 + c] = o;
}

extern "C" void kernel_launch(void* const* d_in, const int* in_sizes, int n_in,
                              void* d_out, int out_size, void* d_ws,
                              size_t ws_size, hipStream_t stream) {
  const float* x = (const float*)d_in[0];
  const int* ei = (const int*)d_in[1];
  const int* src = ei;
  const int* dst = ei + NE;
  const float* bn_in_g = (const float*)d_in[2];
  const float* bn_in_b = (const float*)d_in[3];
  const float* bn1_g = (const float*)d_in[4];
  const float* bn1_b = (const float*)d_in[5];
  const float* bn2_g = (const float*)d_in[6];
  const float* bn2_b = (const float*)d_in[7];
  const float* proj_W = (const float*)d_in[8];
  const float* proj_b = (const float*)d_in[9];
  const float* conv1_W = (const float*)d_in[10];
  const float* conv1_b = (const float*)d_in[11];
  const float* conv2_W = (const float*)d_in[12];
  const float* conv2_b = (const float*)d_in[13];
  float* out = (float*)d_out;

  float* ws = (float*)d_ws;
  float* dinv = ws + OFF_DINV;           // NN floats
  float* st = ws + OFF_ST;               // stats + affine block (2048 floats)
  float* s0 = st;              float* q0 = st + 128;
  float* s1 = st + 256;        float* q1 = st + 384;
  float* s2 = st + 512;        float* q2 = st + 576;
  float* af0 = st + 640;       float* bf0 = st + 768;
  float* af1 = st + 896;       float* bf1 = st + 1024;
  float* af2 = st + 1152;      float* bf2 = st + 1216;
  int* deg = (int*)(ws + OFF_DEG);           // NN ints
  int* rowstart = (int*)(ws + OFF_ROWSTART); // NN+1 ints
  int* cursor = (int*)(ws + OFF_CURSOR);     // NN ints
  int* esrc = (int*)(ws + OFF_ESRC);         // NE ints
  float* B0 = ws + OFF_B0;               // NN*128
  float* B1 = ws + OFF_B1;               // NN*128
  // sequential aliasing: each buffer fully written before read, never
  // read+written by the same kernel
  float* H1 = B0;    // gemm1 out, conv1 in
  float* Y = B1;     // conv1 out, gather1 in
  float* ACC = B0;   // gather1 out (H1 dead), bn1 + conv2 in
  float* Y2 = B1;    // conv2 out (Y dead), gather2 in (NN*64)
  float* ACC2 = B0;  // gather2 out (ACC dead), bn2 + final in (NN*64)

  const int nb_n = (NN + 255) / 256;
  init_k<<<nb_n, 256, 0, stream>>>(deg, st);
  deg_k<<<(NE + 255) / 256, 256, 0, stream>>>(dst, deg);
  scan_k<<<1, 1024, 0, stream>>>(deg, rowstart, cursor, dinv);
  fill_k<<<(NE + 255) / 256, 256, 0, stream>>>(src, dst, cursor, esrc);

  // layer 0: BN(x) folded into GEMM1 staging
  bn_stats_k<128, 0><<<256, 256, 0, stream>>>(x, nullptr, nullptr, s0, q0);
  bn_finalize_k<<<1, 128, 0, stream>>>(s0, q0, bn_in_g, bn_in_b, af0, bf0, 128);

  const int nt64 = (NN + 63) / 64;  // 782 row tiles
  // H1 = relu(BN(x) @ proj_W + proj_b)
  gemm_fused_k<128, 256, 0, 0><<<nt64, 256, 0, stream>>>(
      x, proj_W, proj_b, af0, bf0, nullptr, dinv, H1);
  // conv1: Y = (H1 @ conv1_W) * dinv[row]
  gemm_fused_k<128, 256, 1, 1><<<nt64, 256, 0, stream>>>(
      H1, conv1_W, nullptr, nullptr, nullptr, nullptr, dinv, Y);
  gather_k<128><<<(NN + 7) / 8, 256, 0, stream>>>(rowstart, esrc, Y, ACC);
  // BN1 stats on z1 = dinv[r]*ACC + conv1_b
  bn_stats_k<128, 1><<<256, 256, 0, stream>>>(ACC, dinv, conv1_b, s1, q1);
  bn_finalize_k<<<1, 128, 0, stream>>>(s1, q1, bn1_g, bn1_b, af1, bf1, 128);
  // conv2: input = relu(BN1(z1)) computed in staging; 64 output cols
  gemm_fused_k<64, 128, 2, 1><<<nt64, 128, 0, stream>>>(
      ACC, conv2_W, nullptr, af1, bf1, conv1_b, dinv, Y2);
  gather_k<64><<<(NN + 15) / 16, 256, 0, stream>>>(rowstart, esrc, Y2, ACC2);
  // BN2 stats on z2 = dinv[r]*ACC2 + conv2_b
  bn_stats_k<64, 1><<<256, 256, 0, stream>>>(ACC2, dinv, conv2_b, s2, q2);
  bn_finalize_k<<<1, 128, 0, stream>>>(s2, q2, bn2_g, bn2_b, af2, bf2, 64);
  final_k<<<(NN * 16 + 255) / 256, 256, 0, stream>>>(ACC2, dinv, conv2_b, af2,
                                                     bf2, out);
}

// Round 7
// 388.376 us; speedup vs baseline: 4.8773x; 1.3078x over previous
//
#include <hip/hip_runtime.h>

#define NN 50000
#define NE 640000
#define BNEPS 1e-5f
#define SB 512
#define NBLK ((NN + SB - 1) / SB)  // 98

// workspace layout (float offsets) — total 13,644,800 floats = 54.6 MB
#define OFF_DINV 0
#define OFF_ST 51200
#define OFF_DEG 53248
#define OFF_ROWSTART 103424
#define OFF_CURSOR 153600
#define OFF_ESRC 203776
#define OFF_BSUM 843776
#define OFF_BOFF 843904
#define OFF_B0 844800
#define OFF_B1 7244800

// ---------------- small kernels ----------------
__global__ __launch_bounds__(256) void init_k(int* __restrict__ deg,
                                              float* __restrict__ stats) {
  int i = blockIdx.x * 256 + threadIdx.x;
  if (i < NN) deg[i] = 0;
  if (i < 1024) stats[i] = 0.0f;  // zero BN stat accumulators
}

__global__ __launch_bounds__(256) void deg_k(const int* __restrict__ dst,
                                             int* __restrict__ deg) {
  int e = blockIdx.x * 256 + threadIdx.x;
  if (e < NE) atomicAdd(&deg[dst[e]], 1);
}

// ---- device-wide scan over deg (3 phases, fully parallel) ----
__global__ __launch_bounds__(SB) void block_sum_k(const int* __restrict__ deg,
                                                  int* __restrict__ bsum) {
  __shared__ int sh[SB];
  const int t = threadIdx.x;
  const int i = blockIdx.x * SB + t;
  sh[t] = (i < NN) ? deg[i] : 0;
  __syncthreads();
  for (int off = SB / 2; off > 0; off >>= 1) {
    if (t < off) sh[t] += sh[t + off];
    __syncthreads();
  }
  if (t == 0) bsum[blockIdx.x] = sh[0];
}

__global__ __launch_bounds__(128) void bscan_k(const int* __restrict__ bsum,
                                               int* __restrict__ boff) {
  __shared__ int sh[128];
  const int t = threadIdx.x;
  const int v = (t < NBLK) ? bsum[t] : 0;
  sh[t] = v;
  __syncthreads();
  for (int off = 1; off < 128; off <<= 1) {
    int u = (t >= off) ? sh[t - off] : 0;
    __syncthreads();
    sh[t] += u;
    __syncthreads();
  }
  if (t < NBLK) boff[t] = sh[t] - v;  // exclusive
}

__global__ __launch_bounds__(SB) void scan_fin_k(const int* __restrict__ deg,
                                                 const int* __restrict__ boff,
                                                 int* __restrict__ rowstart,
                                                 int* __restrict__ cursor,
                                                 float* __restrict__ dinv) {
  __shared__ int sh[SB];
  const int t = threadIdx.x;
  const int i = blockIdx.x * SB + t;
  const int v = (i < NN) ? deg[i] : 0;
  sh[t] = v;
  __syncthreads();
  for (int off = 1; off < SB; off <<= 1) {
    int u = (t >= off) ? sh[t - off] : 0;
    __syncthreads();
    sh[t] += u;
    __syncthreads();
  }
  if (i < NN) {
    const int excl = boff[blockIdx.x] + sh[t] - v;
    rowstart[i] = excl;
    cursor[i] = excl;
    dinv[i] = rsqrtf((float)v + 1.0f);  // +1 self loop
  }
  if (i == 0) rowstart[NN] = NE;
}

__global__ __launch_bounds__(256) void fill_k(const int* __restrict__ src,
                                              const int* __restrict__ dst,
                                              int* __restrict__ cursor,
                                              int* __restrict__ esrc) {
  int e = blockIdx.x * 256 + threadIdx.x;
  if (e < NE) {
    int p = atomicAdd(&cursor[dst[e]], 1);
    esrc[p] = src[e];
  }
}

// ---------------- BN stats ----------------
// MODE 0: v = A[r][c]          MODE 1: v = A[r][c]*dinv[r] + cb[c]
template <int NC, int MODE>
__global__ __launch_bounds__(256) void bn_stats_k(const float* __restrict__ A,
                                                  const float* __restrict__ dinv,
                                                  const float* __restrict__ cb,
                                                  float* __restrict__ sums,
                                                  float* __restrict__ sqs) {
  constexpr int CG = NC / 4;
  constexpr int RG = 256 / CG;
  const int tc = threadIdx.x % CG;
  const int tr = threadIdx.x / CG;
  float cb0 = 0, cb1 = 0, cb2 = 0, cb3 = 0;
  if (MODE == 1) {
    cb0 = cb[tc * 4];
    cb1 = cb[tc * 4 + 1];
    cb2 = cb[tc * 4 + 2];
    cb3 = cb[tc * 4 + 3];
  }
  float s0 = 0, s1 = 0, s2 = 0, s3 = 0, q0 = 0, q1 = 0, q2 = 0, q3 = 0;
  for (int r = blockIdx.x * RG + tr; r < NN; r += gridDim.x * RG) {
    float4 v = *(const float4*)&A[(size_t)r * NC + tc * 4];
    if (MODE == 1) {
      float di = dinv[r];
      v.x = fmaf(v.x, di, cb0);
      v.y = fmaf(v.y, di, cb1);
      v.z = fmaf(v.z, di, cb2);
      v.w = fmaf(v.w, di, cb3);
    }
    s0 += v.x; s1 += v.y; s2 += v.z; s3 += v.w;
    q0 += v.x * v.x; q1 += v.y * v.y; q2 += v.z * v.z; q3 += v.w * v.w;
  }
  __shared__ float rs[RG][NC];
  __shared__ float rq[RG][NC];
  rs[tr][tc * 4] = s0; rs[tr][tc * 4 + 1] = s1;
  rs[tr][tc * 4 + 2] = s2; rs[tr][tc * 4 + 3] = s3;
  rq[tr][tc * 4] = q0; rq[tr][tc * 4 + 1] = q1;
  rq[tr][tc * 4 + 2] = q2; rq[tr][tc * 4 + 3] = q3;
  __syncthreads();
  if (tr == 0) {
    for (int j = 0; j < 4; ++j) {
      int c = tc * 4 + j;
      float ts = 0, tq = 0;
      for (int g = 0; g < RG; ++g) { ts += rs[g][c]; tq += rq[g][c]; }
      atomicAdd(&sums[c], ts);
      atomicAdd(&sqs[c], tq);
    }
  }
}

__global__ void bn_finalize_k(const float* __restrict__ sums,
                              const float* __restrict__ sqs,
                              const float* __restrict__ gamma,
                              const float* __restrict__ beta,
                              float* __restrict__ af, float* __restrict__ bf,
                              int nc) {
  int c = threadIdx.x;
  if (c < nc) {
    float m = sums[c] * (1.0f / NN);
    float v = sqs[c] * (1.0f / NN) - m * m;
    float a = gamma[c] * rsqrtf(v + BNEPS);
    af[c] = a;
    bf[c] = beta[c] - m * a;
  }
}

// ---------------- fused GEMM ----------------
// C[row][col] = sum_k pre(A[row][k]) * W[k][col], K = 128 fixed.
// PRE: 0 = af[k]*v+bf[k] ; 1 = v ; 2 = relu(af[k]*(dinv[row]*v+preb[k])+bf[k])
// EPI: 0 = relu(acc + bias[c]) ; 1 = acc*dinv[row]
template <int NC, int NT, int PRE, int EPI>
__global__ __launch_bounds__(NT) void gemm_fused_k(
    const float* __restrict__ A, const float* __restrict__ W,
    const float* __restrict__ bias, const float* __restrict__ af,
    const float* __restrict__ bf, const float* __restrict__ preb,
    const float* __restrict__ dinv, float* __restrict__ O1) {
  constexpr int CG = NC / 4;    // col groups of 4
  constexpr int RG = NT / CG;   // row-thread groups
  constexpr int TR = RG * 8;    // tile rows (= 64)
  constexpr int ATS = TR + 4;   // padded stride: 16B aligned, no bank conflict
  constexpr int KC = 32;
  __shared__ float AT[128 * ATS];
  __shared__ float Wch[KC * NC];

  const int tid = threadIdx.x;
  const int tc = tid % CG;
  const int tr = tid / CG;
  const int row0 = blockIdx.x * TR;

  // stage A^T with pre-op applied
  for (int f = tid; f < TR * 32; f += NT) {
    const int r = f >> 5;
    const int c4 = f & 31;
    const int rg = row0 + r;
    float4 v = make_float4(0.f, 0.f, 0.f, 0.f);
    if (rg < NN) {
      v = *(const float4*)&A[(size_t)rg * 128 + c4 * 4];
      if (PRE == 0) {
        const float4 a4 = *(const float4*)&af[c4 * 4];
        const float4 b4 = *(const float4*)&bf[c4 * 4];
        v.x = fmaf(a4.x, v.x, b4.x);
        v.y = fmaf(a4.y, v.y, b4.y);
        v.z = fmaf(a4.z, v.z, b4.z);
        v.w = fmaf(a4.w, v.w, b4.w);
      } else if (PRE == 2) {
        const float di = dinv[rg];
        const float4 a4 = *(const float4*)&af[c4 * 4];
        const float4 b4 = *(const float4*)&bf[c4 * 4];
        const float4 p4 = *(const float4*)&preb[c4 * 4];
        v.x = fmaxf(fmaf(a4.x, fmaf(di, v.x, p4.x), b4.x), 0.f);
        v.y = fmaxf(fmaf(a4.y, fmaf(di, v.y, p4.y), b4.y), 0.f);
        v.z = fmaxf(fmaf(a4.z, fmaf(di, v.z, p4.z), b4.z), 0.f);
        v.w = fmaxf(fmaf(a4.w, fmaf(di, v.w, p4.w), b4.w), 0.f);
      }
    }
    const int k = c4 * 4;
    AT[(k + 0) * ATS + r] = v.x;
    AT[(k + 1) * ATS + r] = v.y;
    AT[(k + 2) * ATS + r] = v.z;
    AT[(k + 3) * ATS + r] = v.w;
  }

  float acc[8][4];
#pragma unroll
  for (int i = 0; i < 8; ++i)
#pragma unroll
    for (int j = 0; j < 4; ++j) acc[i][j] = 0.f;

  for (int kc = 0; kc < 128 / KC; ++kc) {
    __syncthreads();
    for (int f = tid; f < KC * CG; f += NT) {
      const int k = f / CG;
      const int c4 = f % CG;
      *(float4*)&Wch[k * NC + c4 * 4] =
          *(const float4*)&W[(size_t)(kc * KC + k) * NC + c4 * 4];
    }
    __syncthreads();
#pragma unroll
    for (int k = 0; k < KC; ++k) {
      const float4 b = *(const float4*)&Wch[k * NC + tc * 4];
      const float4 a0 = *(const float4*)&AT[(kc * KC + k) * ATS + tr * 8];
      const float4 a1 = *(const float4*)&AT[(kc * KC + k) * ATS + tr * 8 + 4];
      const float av[8] = {a0.x, a0.y, a0.z, a0.w, a1.x, a1.y, a1.z, a1.w};
#pragma unroll
      for (int i = 0; i < 8; ++i) {
        acc[i][0] = fmaf(av[i], b.x, acc[i][0]);
        acc[i][1] = fmaf(av[i], b.y, acc[i][1]);
        acc[i][2] = fmaf(av[i], b.z, acc[i][2]);
        acc[i][3] = fmaf(av[i], b.w, acc[i][3]);
      }
    }
  }

  float4 b4 = make_float4(0.f, 0.f, 0.f, 0.f);
  if (EPI == 0) b4 = *(const float4*)&bias[tc * 4];
#pragma unroll
  for (int i = 0; i < 8; ++i) {
    const int rg = row0 + tr * 8 + i;
    if (rg < NN) {
      float4 o;
      if (EPI == 0) {
        o.x = fmaxf(acc[i][0] + b4.x, 0.f);
        o.y = fmaxf(acc[i][1] + b4.y, 0.f);
        o.z = fmaxf(acc[i][2] + b4.z, 0.f);
        o.w = fmaxf(acc[i][3] + b4.w, 0.f);
      } else {
        const float s = dinv[rg];
        o.x = acc[i][0] * s;
        o.y = acc[i][1] * s;
        o.z = acc[i][2] * s;
        o.w = acc[i][3] * s;
      }
      *(float4*)&O1[(size_t)rg * NC + tc * 4] = o;
    }
  }
}

// ---------------- CSR gather aggregation ----------------
// ACC[d] = Y[d] (self loop) + sum_{e in in(d)} Y[esrc[e]]
template <int NC>
__global__ __launch_bounds__(256) void gather_k(const int* __restrict__ rowstart,
                                                const int* __restrict__ esrc,
                                                const float* __restrict__ Y,
                                                float* __restrict__ ACC) {
  constexpr int CG = NC / 4;
  constexpr int RG = 256 / CG;
  const int tc = threadIdx.x % CG;
  const int tr = threadIdx.x / CG;
  const int n = blockIdx.x * RG + tr;
  if (n >= NN) return;
  const int c = tc * 4;
  float4 acc = *(const float4*)&Y[(size_t)n * NC + c];
  const int beg = rowstart[n];
  const int end = rowstart[n + 1];
  for (int e = beg; e < end; ++e) {
    const int s = esrc[e];
    const float4 y = *(const float4*)&Y[(size_t)s * NC + c];
    acc.x += y.x; acc.y += y.y; acc.z += y.z; acc.w += y.w;
  }
  *(float4*)&ACC[(size_t)n * NC + c] = acc;
}

// ---------------- final BN apply ----------------
__global__ __launch_bounds__(256) void final_k(const float* __restrict__ ACC2,
                                               const float* __restrict__ dinv,
                                               const float* __restrict__ cb,
                                               const float* __restrict__ af,
                                               const float* __restrict__ bf,
                                               float* __restrict__ out) {
  const int u = blockIdx.x * 256 + threadIdx.x;
  if (u >= NN * 16) return;
  const int r = u >> 4;
  const int c = (u & 15) * 4;
  const float di = dinv[r];
  float4 v = *(const float4*)&ACC2[(size_t)r * 64 + c];
  const float4 c4 = *(const float4*)&cb[c];
  const float4 a4 = *(const float4*)&af[c];
  const float4 b4 = *(const float4*)&bf[c];
  float4 o;
  o.x = fmaf(a4.x, fmaf(v.x, di, c4.x), b4.x);
  o.y = fmaf(a4.y, fmaf(v.y, di, c4.y), b4.y);
  o.z = fmaf(a4.z, fmaf(v.z, di, c4.z), b4.z);
  o.w = fmaf(a4.w, fmaf(v.w, di, c4.w), b4.w);
  *(float4*)&out[(size_t)r * 64 + c] = o;
}

extern "C" void kernel_launch(void* const* d_in, const int* in_sizes, int n_in,
                              void* d_out, int out_size, void* d_ws,
                              size_t ws_size, hipStream_t stream) {
  const float* x = (const float*)d_in[0];
  const int* ei = (const int*)d_in[1];
  const int* src = ei;
  const int* dst = ei + NE;
  const float* bn_in_g = (const float*)d_in[2];
  const float* bn_in_b = (const float*)d_in[3];
  const float* bn1_g = (const float*)d_in[4];
  const float* bn1_b = (const float*)d_in[5];
  const float* bn2_g = (const float*)d_in[6];
  const float* bn2_b = (const float*)d_in[7];
  const float* proj_W = (const float*)d_in[8];
  const float* proj_b = (const float*)d_in[9];
  const float* conv1_W = (const float*)d_in[10];
  const float* conv1_b = (const float*)d_in[11];
  const float* conv2_W = (const float*)d_in[12];
  const float* conv2_b = (const float*)d_in[13];
  float* out = (float*)d_out;

  float* ws = (float*)d_ws;
  float* dinv = ws + OFF_DINV;           // NN floats
  float* st = ws + OFF_ST;               // stats + affine block (2048 floats)
  float* s0 = st;              float* q0 = st + 128;
  float* s1 = st + 256;        float* q1 = st + 384;
  float* s2 = st + 512;        float* q2 = st + 576;
  float* af0 = st + 640;       float* bf0 = st + 768;
  float* af1 = st + 896;       float* bf1 = st + 1024;
  float* af2 = st + 1152;      float* bf2 = st + 1216;
  int* deg = (int*)(ws + OFF_DEG);           // NN ints
  int* rowstart = (int*)(ws + OFF_ROWSTART); // NN+1 ints
  int* cursor = (int*)(ws + OFF_CURSOR);     // NN ints
  int* esrc = (int*)(ws + OFF_ESRC);         // NE ints
  int* bsum = (int*)(ws + OFF_BSUM);         // NBLK ints
  int* boff = (int*)(ws + OFF_BOFF);         // NBLK ints
  float* B0 = ws + OFF_B0;               // NN*128
  float* B1 = ws + OFF_B1;               // NN*128
  // sequential aliasing: each buffer fully written before read, never
  // read+written by the same kernel
  float* H1 = B0;    // gemm1 out, conv1 in
  float* Y = B1;     // conv1 out, gather1 in
  float* ACC = B0;   // gather1 out (H1 dead), bn1 + conv2 in
  float* Y2 = B1;    // conv2 out (Y dead), gather2 in (NN*64)
  float* ACC2 = B0;  // gather2 out (ACC dead), bn2 + final in (NN*64)

  const int nb_n = (NN + 255) / 256;
  init_k<<<nb_n, 256, 0, stream>>>(deg, st);
  deg_k<<<(NE + 255) / 256, 256, 0, stream>>>(dst, deg);
  block_sum_k<<<NBLK, SB, 0, stream>>>(deg, bsum);
  bscan_k<<<1, 128, 0, stream>>>(bsum, boff);
  scan_fin_k<<<NBLK, SB, 0, stream>>>(deg, boff, rowstart, cursor, dinv);
  fill_k<<<(NE + 255) / 256, 256, 0, stream>>>(src, dst, cursor, esrc);

  // layer 0: BN(x) folded into GEMM1 staging
  bn_stats_k<128, 0><<<256, 256, 0, stream>>>(x, nullptr, nullptr, s0, q0);
  bn_finalize_k<<<1, 128, 0, stream>>>(s0, q0, bn_in_g, bn_in_b, af0, bf0, 128);

  const int nt64 = (NN + 63) / 64;  // 782 row tiles
  // H1 = relu(BN(x) @ proj_W + proj_b)
  gemm_fused_k<128, 256, 0, 0><<<nt64, 256, 0, stream>>>(
      x, proj_W, proj_b, af0, bf0, nullptr, dinv, H1);
  // conv1: Y = (H1 @ conv1_W) * dinv[row]
  gemm_fused_k<128, 256, 1, 1><<<nt64, 256, 0, stream>>>(
      H1, conv1_W, nullptr, nullptr, nullptr, nullptr, dinv, Y);
  gather_k<128><<<(NN + 7) / 8, 256, 0, stream>>>(rowstart, esrc, Y, ACC);
  // BN1 stats on z1 = dinv[r]*ACC + conv1_b
  bn_stats_k<128, 1><<<256, 256, 0, stream>>>(ACC, dinv, conv1_b, s1, q1);
  bn_finalize_k<<<1, 128, 0, stream>>>(s1, q1, bn1_g, bn1_b, af1, bf1, 128);
  // conv2: input = relu(BN1(z1)) computed in staging; 64 output cols
  gemm_fused_k<64, 128, 2, 1><<<nt64, 128, 0, stream>>>(
      ACC, conv2_W, nullptr, af1, bf1, conv1_b, dinv, Y2);
  gather_k<64><<<(NN + 15) / 16, 256, 0, stream>>>(rowstart, esrc, Y2, ACC2);
  // BN2 stats on z2 = dinv[r]*ACC2 + conv2_b
  bn_stats_k<64, 1><<<256, 256, 0, stream>>>(ACC2, dinv, conv2_b, s2, q2);
  bn_finalize_k<<<1, 128, 0, stream>>>(s2, q2, bn2_g, bn2_b, af2, bf2, 64);
  final_k<<<(NN * 16 + 255) / 256, 256, 0, stream>>>(ACC2, dinv, conv2_b, af2,
                                                     bf2, out);
}

// Round 9
// 348.377 us; speedup vs baseline: 5.4373x; 1.1148x over previous
//
#include <hip/hip_runtime.h>

#define NN 50000
#define NE 640000
#define BNEPS 1e-5f
#define SB 512
#define NBLK ((NN + SB - 1) / SB)  // 98

// workspace layout (float offsets) — total 13,644,800 floats = 54.6 MB
#define OFF_DINV 0
#define OFF_ST 51200
#define OFF_DEG 53248
#define OFF_ROWSTART 103424
#define OFF_CURSOR 153600
#define OFF_ESRC 203776
#define OFF_BSUM 843776
#define OFF_BOFF 843904
#define OFF_B0 844800
#define OFF_B1 7244800

// ---- bf16 helpers ----
__device__ __forceinline__ float uplo(unsigned int u) {
  unsigned int v = u << 16;
  return __builtin_bit_cast(float, v);
}
__device__ __forceinline__ float uphi(unsigned int u) {
  unsigned int v = u & 0xffff0000u;
  return __builtin_bit_cast(float, v);
}
__device__ __forceinline__ unsigned int f2bf(float f) {
  unsigned int u = __builtin_bit_cast(unsigned int, f);
  return (u + 0x7fffu + ((u >> 16) & 1u)) >> 16;  // RNE
}

// ---------------- small kernels ----------------
__global__ __launch_bounds__(256) void init_k(int* __restrict__ deg,
                                              float* __restrict__ stats) {
  int i = blockIdx.x * 256 + threadIdx.x;
  if (i < NN) deg[i] = 0;
  if (i < 1024) stats[i] = 0.0f;  // zero BN stat accumulators
}

__global__ __launch_bounds__(256) void deg_k(const int* __restrict__ dst,
                                             int* __restrict__ deg) {
  int e = blockIdx.x * 256 + threadIdx.x;
  if (e < NE) atomicAdd(&deg[dst[e]], 1);
}

// ---- device-wide scan over deg (3 phases, fully parallel) ----
__global__ __launch_bounds__(SB) void block_sum_k(const int* __restrict__ deg,
                                                  int* __restrict__ bsum) {
  __shared__ int sh[SB];
  const int t = threadIdx.x;
  const int i = blockIdx.x * SB + t;
  sh[t] = (i < NN) ? deg[i] : 0;
  __syncthreads();
  for (int off = SB / 2; off > 0; off >>= 1) {
    if (t < off) sh[t] += sh[t + off];
    __syncthreads();
  }
  if (t == 0) bsum[blockIdx.x] = sh[0];
}

__global__ __launch_bounds__(128) void bscan_k(const int* __restrict__ bsum,
                                               int* __restrict__ boff) {
  __shared__ int sh[128];
  const int t = threadIdx.x;
  const int v = (t < NBLK) ? bsum[t] : 0;
  sh[t] = v;
  __syncthreads();
  for (int off = 1; off < 128; off <<= 1) {
    int u = (t >= off) ? sh[t - off] : 0;
    __syncthreads();
    sh[t] += u;
    __syncthreads();
  }
  if (t < NBLK) boff[t] = sh[t] - v;  // exclusive
}

__global__ __launch_bounds__(SB) void scan_fin_k(const int* __restrict__ deg,
                                                 const int* __restrict__ boff,
                                                 int* __restrict__ rowstart,
                                                 int* __restrict__ cursor,
                                                 float* __restrict__ dinv) {
  __shared__ int sh[SB];
  const int t = threadIdx.x;
  const int i = blockIdx.x * SB + t;
  const int v = (i < NN) ? deg[i] : 0;
  sh[t] = v;
  __syncthreads();
  for (int off = 1; off < SB; off <<= 1) {
    int u = (t >= off) ? sh[t - off] : 0;
    __syncthreads();
    sh[t] += u;
    __syncthreads();
  }
  if (i < NN) {
    const int excl = boff[blockIdx.x] + sh[t] - v;
    rowstart[i] = excl;
    cursor[i] = excl;
    dinv[i] = rsqrtf((float)v + 1.0f);  // +1 self loop
  }
  if (i == 0) rowstart[NN] = NE;
}

__global__ __launch_bounds__(256) void fill_k(const int* __restrict__ src,
                                              const int* __restrict__ dst,
                                              int* __restrict__ cursor,
                                              int* __restrict__ esrc) {
  int e = blockIdx.x * 256 + threadIdx.x;
  if (e < NE) {
    int p = atomicAdd(&cursor[dst[e]], 1);
    esrc[p] = src[e];
  }
}

// ---------------- BN stats ----------------
// MODE 0: v = A[r][c]          MODE 1: v = A[r][c]*dinv[r] + cb[c]
template <int NC, int MODE>
__global__ __launch_bounds__(256) void bn_stats_k(const float* __restrict__ A,
                                                  const float* __restrict__ dinv,
                                                  const float* __restrict__ cb,
                                                  float* __restrict__ sums,
                                                  float* __restrict__ sqs) {
  constexpr int CG = NC / 4;
  constexpr int RG = 256 / CG;
  const int tc = threadIdx.x % CG;
  const int tr = threadIdx.x / CG;
  float cb0 = 0, cb1 = 0, cb2 = 0, cb3 = 0;
  if (MODE == 1) {
    cb0 = cb[tc * 4];
    cb1 = cb[tc * 4 + 1];
    cb2 = cb[tc * 4 + 2];
    cb3 = cb[tc * 4 + 3];
  }
  float s0 = 0, s1 = 0, s2 = 0, s3 = 0, q0 = 0, q1 = 0, q2 = 0, q3 = 0;
  for (int r = blockIdx.x * RG + tr; r < NN; r += gridDim.x * RG) {
    float4 v = *(const float4*)&A[(size_t)r * NC + tc * 4];
    if (MODE == 1) {
      float di = dinv[r];
      v.x = fmaf(v.x, di, cb0);
      v.y = fmaf(v.y, di, cb1);
      v.z = fmaf(v.z, di, cb2);
      v.w = fmaf(v.w, di, cb3);
    }
    s0 += v.x; s1 += v.y; s2 += v.z; s3 += v.w;
    q0 += v.x * v.x; q1 += v.y * v.y; q2 += v.z * v.z; q3 += v.w * v.w;
  }
  __shared__ float rs[RG][NC];
  __shared__ float rq[RG][NC];
  rs[tr][tc * 4] = s0; rs[tr][tc * 4 + 1] = s1;
  rs[tr][tc * 4 + 2] = s2; rs[tr][tc * 4 + 3] = s3;
  rq[tr][tc * 4] = q0; rq[tr][tc * 4 + 1] = q1;
  rq[tr][tc * 4 + 2] = q2; rq[tr][tc * 4 + 3] = q3;
  __syncthreads();
  if (tr == 0) {
    for (int j = 0; j < 4; ++j) {
      int c = tc * 4 + j;
      float ts = 0, tq = 0;
      for (int g = 0; g < RG; ++g) { ts += rs[g][c]; tq += rq[g][c]; }
      atomicAdd(&sums[c], ts);
      atomicAdd(&sqs[c], tq);
    }
  }
}

__global__ void bn_finalize_k(const float* __restrict__ sums,
                              const float* __restrict__ sqs,
                              const float* __restrict__ gamma,
                              const float* __restrict__ beta,
                              float* __restrict__ af, float* __restrict__ bf,
                              int nc) {
  int c = threadIdx.x;
  if (c < nc) {
    float m = sums[c] * (1.0f / NN);
    float v = sqs[c] * (1.0f / NN) - m * m;
    float a = gamma[c] * rsqrtf(v + BNEPS);
    af[c] = a;
    bf[c] = beta[c] - m * a;
  }
}

// ---------------- fused GEMM ----------------
// C[row][col] = sum_k pre(A[row][k]) * W[k][col], K = 128 fixed.
// PRE: 0 = af[k]*v+bf[k] ; 1 = v ; 2 = relu(af[k]*(dinv[row]*v+preb[k])+bf[k])
// EPI: 0 = relu(acc + bias[c]) -> f32 ; 1 = acc*dinv[row] -> bf16
template <int NC, int NT, int PRE, int EPI>
__global__ __launch_bounds__(NT) void gemm_fused_k(
    const float* __restrict__ A, const float* __restrict__ W,
    const float* __restrict__ bias, const float* __restrict__ af,
    const float* __restrict__ bf, const float* __restrict__ preb,
    const float* __restrict__ dinv, void* __restrict__ O1) {
  constexpr int CG = NC / 4;    // col groups of 4
  constexpr int RG = NT / CG;   // row-thread groups
  constexpr int TR = RG * 8;    // tile rows (= 64)
  constexpr int ATS = TR + 4;   // padded stride: 16B aligned, no bank conflict
  constexpr int KC = 32;
  __shared__ float AT[128 * ATS];
  __shared__ float Wch[KC * NC];

  const int tid = threadIdx.x;
  const int tc = tid % CG;
  const int tr = tid / CG;
  const int row0 = blockIdx.x * TR;

  // stage A^T with pre-op applied
  for (int f = tid; f < TR * 32; f += NT) {
    const int r = f >> 5;
    const int c4 = f & 31;
    const int rg = row0 + r;
    float4 v = make_float4(0.f, 0.f, 0.f, 0.f);
    if (rg < NN) {
      v = *(const float4*)&A[(size_t)rg * 128 + c4 * 4];
      if (PRE == 0) {
        const float4 a4 = *(const float4*)&af[c4 * 4];
        const float4 b4 = *(const float4*)&bf[c4 * 4];
        v.x = fmaf(a4.x, v.x, b4.x);
        v.y = fmaf(a4.y, v.y, b4.y);
        v.z = fmaf(a4.z, v.z, b4.z);
        v.w = fmaf(a4.w, v.w, b4.w);
      } else if (PRE == 2) {
        const float di = dinv[rg];
        const float4 a4 = *(const float4*)&af[c4 * 4];
        const float4 b4 = *(const float4*)&bf[c4 * 4];
        const float4 p4 = *(const float4*)&preb[c4 * 4];
        v.x = fmaxf(fmaf(a4.x, fmaf(di, v.x, p4.x), b4.x), 0.f);
        v.y = fmaxf(fmaf(a4.y, fmaf(di, v.y, p4.y), b4.y), 0.f);
        v.z = fmaxf(fmaf(a4.z, fmaf(di, v.z, p4.z), b4.z), 0.f);
        v.w = fmaxf(fmaf(a4.w, fmaf(di, v.w, p4.w), b4.w), 0.f);
      }
    }
    const int k = c4 * 4;
    AT[(k + 0) * ATS + r] = v.x;
    AT[(k + 1) * ATS + r] = v.y;
    AT[(k + 2) * ATS + r] = v.z;
    AT[(k + 3) * ATS + r] = v.w;
  }

  float acc[8][4];
#pragma unroll
  for (int i = 0; i < 8; ++i)
#pragma unroll
    for (int j = 0; j < 4; ++j) acc[i][j] = 0.f;

  for (int kc = 0; kc < 128 / KC; ++kc) {
    __syncthreads();
    for (int f = tid; f < KC * CG; f += NT) {
      const int k = f / CG;
      const int c4 = f % CG;
      *(float4*)&Wch[k * NC + c4 * 4] =
          *(const float4*)&W[(size_t)(kc * KC + k) * NC + c4 * 4];
    }
    __syncthreads();
#pragma unroll
    for (int k = 0; k < KC; ++k) {
      const float4 b = *(const float4*)&Wch[k * NC + tc * 4];
      const float4 a0 = *(const float4*)&AT[(kc * KC + k) * ATS + tr * 8];
      const float4 a1 = *(const float4*)&AT[(kc * KC + k) * ATS + tr * 8 + 4];
      const float av[8] = {a0.x, a0.y, a0.z, a0.w, a1.x, a1.y, a1.z, a1.w};
#pragma unroll
      for (int i = 0; i < 8; ++i) {
        acc[i][0] = fmaf(av[i], b.x, acc[i][0]);
        acc[i][1] = fmaf(av[i], b.y, acc[i][1]);
        acc[i][2] = fmaf(av[i], b.z, acc[i][2]);
        acc[i][3] = fmaf(av[i], b.w, acc[i][3]);
      }
    }
  }

  float4 b4 = make_float4(0.f, 0.f, 0.f, 0.f);
  if (EPI == 0) b4 = *(const float4*)&bias[tc * 4];
#pragma unroll
  for (int i = 0; i < 8; ++i) {
    const int rg = row0 + tr * 8 + i;
    if (rg < NN) {
      if (EPI == 0) {
        float4 o;
        o.x = fmaxf(acc[i][0] + b4.x, 0.f);
        o.y = fmaxf(acc[i][1] + b4.y, 0.f);
        o.z = fmaxf(acc[i][2] + b4.z, 0.f);
        o.w = fmaxf(acc[i][3] + b4.w, 0.f);
        *(float4*)&((float*)O1)[(size_t)rg * NC + tc * 4] = o;
      } else {
        const float s = dinv[rg];
        uint2 w;
        w.x = f2bf(acc[i][0] * s) | (f2bf(acc[i][1] * s) << 16);
        w.y = f2bf(acc[i][2] * s) | (f2bf(acc[i][3] * s) << 16);
        *(uint2*)&((unsigned short*)O1)[(size_t)rg * NC + tc * 4] = w;
      }
    }
  }
}

// ---------------- CSR gather aggregation (bf16 messages, f32 accum) ----
// ACC[d] = Y[d] (self loop) + sum_{e in in(d)} Y[esrc[e]]
template <int NC>
__global__ __launch_bounds__(256) void gather_bf_k(
    const int* __restrict__ rowstart, const int* __restrict__ esrc,
    const unsigned short* __restrict__ Y, float* __restrict__ ACC) {
  constexpr int CG = NC / 8;      // lanes per row (16 or 8), 16B bf16x8 each
  constexpr int RG = 256 / CG;    // rows per block (16 or 32)
  const int tc = threadIdx.x % CG;
  const int tr = threadIdx.x / CG;
  const int n = blockIdx.x * RG + tr;
  if (n >= NN) return;
  const int c = tc * 8;
  float a[8];
  {
    const uint4 p = *(const uint4*)&Y[(size_t)n * NC + c];
    a[0] = uplo(p.x); a[1] = uphi(p.x);
    a[2] = uplo(p.y); a[3] = uphi(p.y);
    a[4] = uplo(p.z); a[5] = uphi(p.z);
    a[6] = uplo(p.w); a[7] = uphi(p.w);
  }
  const int beg = rowstart[n];
  const int end = rowstart[n + 1];
  int e = beg;
  for (; e + 2 <= end; e += 2) {
    const int s0 = esrc[e];
    const int s1 = esrc[e + 1];
    const uint4 q0 = *(const uint4*)&Y[(size_t)s0 * NC + c];
    const uint4 q1 = *(const uint4*)&Y[(size_t)s1 * NC + c];
    a[0] += uplo(q0.x); a[1] += uphi(q0.x);
    a[2] += uplo(q0.y); a[3] += uphi(q0.y);
    a[4] += uplo(q0.z); a[5] += uphi(q0.z);
    a[6] += uplo(q0.w); a[7] += uphi(q0.w);
    a[0] += uplo(q1.x); a[1] += uphi(q1.x);
    a[2] += uplo(q1.y); a[3] += uphi(q1.y);
    a[4] += uplo(q1.z); a[5] += uphi(q1.z);
    a[6] += uplo(q1.w); a[7] += uphi(q1.w);
  }
  if (e < end) {
    const int s0 = esrc[e];
    const uint4 q0 = *(const uint4*)&Y[(size_t)s0 * NC + c];
    a[0] += uplo(q0.x); a[1] += uphi(q0.x);
    a[2] += uplo(q0.y); a[3] += uphi(q0.y);
    a[4] += uplo(q0.z); a[5] += uphi(q0.z);
    a[6] += uplo(q0.w); a[7] += uphi(q0.w);
  }
  float4 o0 = make_float4(a[0], a[1], a[2], a[3]);
  float4 o1 = make_float4(a[4], a[5], a[6], a[7]);
  *(float4*)&ACC[(size_t)n * NC + c] = o0;
  *(float4*)&ACC[(size_t)n * NC + c + 4] = o1;
}

// ---------------- final BN apply ----------------
__global__ __launch_bounds__(256) void final_k(const float* __restrict__ ACC2,
                                               const float* __restrict__ dinv,
                                               const float* __restrict__ cb,
                                               const float* __restrict__ af,
                                               const float* __restrict__ bf,
                                               float* __restrict__ out) {
  const int u = blockIdx.x * 256 + threadIdx.x;
  if (u >= NN * 16) return;
  const int r = u >> 4;
  const int c = (u & 15) * 4;
  const float di = dinv[r];
  float4 v = *(const float4*)&ACC2[(size_t)r * 64 + c];
  const float4 c4 = *(const float4*)&cb[c];
  const float4 a4 = *(const float4*)&af[c];
  const float4 b4 = *(const float4*)&bf[c];
  float4 o;
  o.x = fmaf(a4.x, fmaf(v.x, di, c4.x), b4.x);
  o.y = fmaf(a4.y, fmaf(v.y, di, c4.y), b4.y);
  o.z = fmaf(a4.z, fmaf(v.z, di, c4.z), b4.z);
  o.w = fmaf(a4.w, fmaf(v.w, di, c4.w), b4.w);
  *(float4*)&out[(size_t)r * 64 + c] = o;
}

extern "C" void kernel_launch(void* const* d_in, const int* in_sizes, int n_in,
                              void* d_out, int out_size, void* d_ws,
                              size_t ws_size, hipStream_t stream) {
  const float* x = (const float*)d_in[0];
  const int* ei = (const int*)d_in[1];
  const int* src = ei;
  const int* dst = ei + NE;
  const float* bn_in_g = (const float*)d_in[2];
  const float* bn_in_b = (const float*)d_in[3];
  const float* bn1_g = (const float*)d_in[4];
  const float* bn1_b = (const float*)d_in[5];
  const float* bn2_g = (const float*)d_in[6];
  const float* bn2_b = (const float*)d_in[7];
  const float* proj_W = (const float*)d_in[8];
  const float* proj_b = (const float*)d_in[9];
  const float* conv1_W = (const float*)d_in[10];
  const float* conv1_b = (const float*)d_in[11];
  const float* conv2_W = (const float*)d_in[12];
  const float* conv2_b = (const float*)d_in[13];
  float* out = (float*)d_out;

  float* ws = (float*)d_ws;
  float* dinv = ws + OFF_DINV;           // NN floats
  float* st = ws + OFF_ST;               // stats + affine block (2048 floats)
  float* s0 = st;              float* q0 = st + 128;
  float* s1 = st + 256;        float* q1 = st + 384;
  float* s2 = st + 512;        float* q2 = st + 576;
  float* af0 = st + 640;       float* bf0 = st + 768;
  float* af1 = st + 896;       float* bf1 = st + 1024;
  float* af2 = st + 1152;      float* bf2 = st + 1216;
  int* deg = (int*)(ws + OFF_DEG);           // NN ints
  int* rowstart = (int*)(ws + OFF_ROWSTART); // NN+1 ints
  int* cursor = (int*)(ws + OFF_CURSOR);     // NN ints
  int* esrc = (int*)(ws + OFF_ESRC);         // NE ints
  int* bsum = (int*)(ws + OFF_BSUM);         // NBLK ints
  int* boff = (int*)(ws + OFF_BOFF);         // NBLK ints
  float* B0 = ws + OFF_B0;               // NN*128 f32
  float* B1 = ws + OFF_B1;               // NN*128 f32 (or NN*128 bf16)
  // sequential aliasing: each buffer generation fully written before read
  float* H1 = B0;                           // gemm1 out (f32), conv1 in
  unsigned short* Ybf = (unsigned short*)B1;   // conv1 out (bf16), gather1 in
  float* ACC = B0;                          // gather1 out (H1 dead), bn1+conv2 in
  unsigned short* Y2bf = (unsigned short*)B1;  // conv2 out (bf16, Y dead), gather2 in
  float* ACC2 = B0;                         // gather2 out (ACC dead), bn2+final in

  const int nb_n = (NN + 255) / 256;
  init_k<<<nb_n, 256, 0, stream>>>(deg, st);
  deg_k<<<(NE + 255) / 256, 256, 0, stream>>>(dst, deg);
  block_sum_k<<<NBLK, SB, 0, stream>>>(deg, bsum);
  bscan_k<<<1, 128, 0, stream>>>(bsum, boff);
  scan_fin_k<<<NBLK, SB, 0, stream>>>(deg, boff, rowstart, cursor, dinv);
  fill_k<<<(NE + 255) / 256, 256, 0, stream>>>(src, dst, cursor, esrc);

  // layer 0: BN(x) folded into GEMM1 staging
  bn_stats_k<128, 0><<<256, 256, 0, stream>>>(x, nullptr, nullptr, s0, q0);
  bn_finalize_k<<<1, 128, 0, stream>>>(s0, q0, bn_in_g, bn_in_b, af0, bf0, 128);

  const int nt64 = (NN + 63) / 64;  // 782 row tiles
  // H1 = relu(BN(x) @ proj_W + proj_b)  [f32 out]
  gemm_fused_k<128, 256, 0, 0><<<nt64, 256, 0, stream>>>(
      x, proj_W, proj_b, af0, bf0, nullptr, dinv, H1);
  // conv1: Ybf = bf16((H1 @ conv1_W) * dinv[row])
  gemm_fused_k<128, 256, 1, 1><<<nt64, 256, 0, stream>>>(
      H1, conv1_W, nullptr, nullptr, nullptr, nullptr, dinv, Ybf);
  gather_bf_k<128><<<(NN + 15) / 16, 256, 0, stream>>>(rowstart, esrc, Ybf, ACC);
  // BN1 stats on z1 = dinv[r]*ACC + conv1_b
  bn_stats_k<128, 1><<<256, 256, 0, stream>>>(ACC, dinv, conv1_b, s1, q1);
  bn_finalize_k<<<1, 128, 0, stream>>>(s1, q1, bn1_g, bn1_b, af1, bf1, 128);
  // conv2: input = relu(BN1(z1)) computed in staging; bf16 out
  gemm_fused_k<64, 128, 2, 1><<<nt64, 128, 0, stream>>>(
      ACC, conv2_W, nullptr, af1, bf1, conv1_b, dinv, Y2bf);
  gather_bf_k<64><<<(NN + 31) / 32, 256, 0, stream>>>(rowstart, esrc, Y2bf, ACC2);
  // BN2 stats on z2 = dinv[r]*ACC2 + conv2_b
  bn_stats_k<64, 1><<<256, 256, 0, stream>>>(ACC2, dinv, conv2_b, s2, q2);
  bn_finalize_k<<<1, 128, 0, stream>>>(s2, q2, bn2_g, bn2_b, af2, bf2, 64);
  final_k<<<(NN * 16 + 255) / 256, 256, 0, stream>>>(ACC2, dinv, conv2_b, af2,
                                                     bf2, out);
}

// Round 10
// 291.490 us; speedup vs baseline: 6.4984x; 1.1952x over previous
//
#include <hip/hip_runtime.h>

#define NN 50000
#define NE 640000
#define BNEPS 1e-5f
#define SB 512
#define NBLK ((NN + SB - 1) / SB)  // 98

// workspace layout (float offsets) — total 13,665,280 floats = 54.7 MB
#define OFF_DINV 0
#define OFF_ST 51200
#define OFF_DEG 53248
#define OFF_ROWSTART 103424
#define OFF_CURSOR 153600
#define OFF_ESRC 203776
#define OFF_BSUM 843776
#define OFF_BOFF 843904
#define OFF_B0 844800
#define OFF_B1 7244800
#define OFF_WT0 13644800
#define OFF_WT1 13652992
#define OFF_WT2 13661184

typedef __attribute__((ext_vector_type(8))) __bf16 bf16x8;
typedef __attribute__((ext_vector_type(4))) float f32x4;

// ---- bf16 helpers ----
__device__ __forceinline__ float uplo(unsigned int u) {
  unsigned int v = u << 16;
  return __builtin_bit_cast(float, v);
}
__device__ __forceinline__ float uphi(unsigned int u) {
  unsigned int v = u & 0xffff0000u;
  return __builtin_bit_cast(float, v);
}
__device__ __forceinline__ unsigned int f2bf(float f) {
  unsigned int u = __builtin_bit_cast(unsigned int, f);
  return (u + 0x7fffu + ((u >> 16) & 1u)) >> 16;  // RNE
}

// ---------------- small kernels ----------------
__global__ __launch_bounds__(256) void init_k(int* __restrict__ deg,
                                              float* __restrict__ stats) {
  int i = blockIdx.x * 256 + threadIdx.x;
  if (i < NN) deg[i] = 0;
  if (i < 1024) stats[i] = 0.0f;
}

__global__ __launch_bounds__(256) void deg_k(const int* __restrict__ dst,
                                             int* __restrict__ deg) {
  int e = blockIdx.x * 256 + threadIdx.x;
  if (e < NE) atomicAdd(&deg[dst[e]], 1);
}

// ---- device-wide scan over deg ----
__global__ __launch_bounds__(SB) void block_sum_k(const int* __restrict__ deg,
                                                  int* __restrict__ bsum) {
  __shared__ int sh[SB];
  const int t = threadIdx.x;
  const int i = blockIdx.x * SB + t;
  sh[t] = (i < NN) ? deg[i] : 0;
  __syncthreads();
  for (int off = SB / 2; off > 0; off >>= 1) {
    if (t < off) sh[t] += sh[t + off];
    __syncthreads();
  }
  if (t == 0) bsum[blockIdx.x] = sh[0];
}

__global__ __launch_bounds__(128) void bscan_k(const int* __restrict__ bsum,
                                               int* __restrict__ boff) {
  __shared__ int sh[128];
  const int t = threadIdx.x;
  const int v = (t < NBLK) ? bsum[t] : 0;
  sh[t] = v;
  __syncthreads();
  for (int off = 1; off < 128; off <<= 1) {
    int u = (t >= off) ? sh[t - off] : 0;
    __syncthreads();
    sh[t] += u;
    __syncthreads();
  }
  if (t < NBLK) boff[t] = sh[t] - v;
}

__global__ __launch_bounds__(SB) void scan_fin_k(const int* __restrict__ deg,
                                                 const int* __restrict__ boff,
                                                 int* __restrict__ rowstart,
                                                 int* __restrict__ cursor,
                                                 float* __restrict__ dinv) {
  __shared__ int sh[SB];
  const int t = threadIdx.x;
  const int i = blockIdx.x * SB + t;
  const int v = (i < NN) ? deg[i] : 0;
  sh[t] = v;
  __syncthreads();
  for (int off = 1; off < SB; off <<= 1) {
    int u = (t >= off) ? sh[t - off] : 0;
    __syncthreads();
    sh[t] += u;
    __syncthreads();
  }
  if (i < NN) {
    const int excl = boff[blockIdx.x] + sh[t] - v;
    rowstart[i] = excl;
    cursor[i] = excl;
    dinv[i] = rsqrtf((float)v + 1.0f);
  }
  if (i == 0) rowstart[NN] = NE;
}

__global__ __launch_bounds__(256) void fill_k(const int* __restrict__ src,
                                              const int* __restrict__ dst,
                                              int* __restrict__ cursor,
                                              int* __restrict__ esrc) {
  int e = blockIdx.x * 256 + threadIdx.x;
  if (e < NE) {
    int p = atomicAdd(&cursor[dst[e]], 1);
    esrc[p] = src[e];
  }
}

// ---- weight transpose: W[128][nc] f32 -> Wt[nc][128] bf16, 3 weights ----
__global__ __launch_bounds__(256) void wtrans3_k(
    const float* __restrict__ W0, const float* __restrict__ W1,
    const float* __restrict__ W2, unsigned short* __restrict__ T0,
    unsigned short* __restrict__ T1, unsigned short* __restrict__ T2) {
  int f = blockIdx.x * 256 + threadIdx.x;
  if (f < 16384) {
    int k = f >> 7, n = f & 127;
    T0[n * 128 + k] = (unsigned short)f2bf(W0[f]);
  } else if (f < 32768) {
    int g = f - 16384;
    int k = g >> 7, n = g & 127;
    T1[n * 128 + k] = (unsigned short)f2bf(W1[g]);
  } else if (f < 40960) {
    int g = f - 32768;
    int k = g >> 6, n = g & 63;
    T2[n * 128 + k] = (unsigned short)f2bf(W2[g]);
  }
}

// ---------------- BN stats ----------------
// MODE 0: v = A[r][c]          MODE 1: v = A[r][c]*dinv[r] + cb[c]
template <int NC, int MODE>
__global__ __launch_bounds__(256) void bn_stats_k(const float* __restrict__ A,
                                                  const float* __restrict__ dinv,
                                                  const float* __restrict__ cb,
                                                  float* __restrict__ sums,
                                                  float* __restrict__ sqs) {
  constexpr int CG = NC / 4;
  constexpr int RG = 256 / CG;
  const int tc = threadIdx.x % CG;
  const int tr = threadIdx.x / CG;
  float cb0 = 0, cb1 = 0, cb2 = 0, cb3 = 0;
  if (MODE == 1) {
    cb0 = cb[tc * 4];
    cb1 = cb[tc * 4 + 1];
    cb2 = cb[tc * 4 + 2];
    cb3 = cb[tc * 4 + 3];
  }
  float s0 = 0, s1 = 0, s2 = 0, s3 = 0, q0 = 0, q1 = 0, q2 = 0, q3 = 0;
  for (int r = blockIdx.x * RG + tr; r < NN; r += gridDim.x * RG) {
    float4 v = *(const float4*)&A[(size_t)r * NC + tc * 4];
    if (MODE == 1) {
      float di = dinv[r];
      v.x = fmaf(v.x, di, cb0);
      v.y = fmaf(v.y, di, cb1);
      v.z = fmaf(v.z, di, cb2);
      v.w = fmaf(v.w, di, cb3);
    }
    s0 += v.x; s1 += v.y; s2 += v.z; s3 += v.w;
    q0 += v.x * v.x; q1 += v.y * v.y; q2 += v.z * v.z; q3 += v.w * v.w;
  }
  __shared__ float rs[RG][NC];
  __shared__ float rq[RG][NC];
  rs[tr][tc * 4] = s0; rs[tr][tc * 4 + 1] = s1;
  rs[tr][tc * 4 + 2] = s2; rs[tr][tc * 4 + 3] = s3;
  rq[tr][tc * 4] = q0; rq[tr][tc * 4 + 1] = q1;
  rq[tr][tc * 4 + 2] = q2; rq[tr][tc * 4 + 3] = q3;
  __syncthreads();
  if (tr == 0) {
    for (int j = 0; j < 4; ++j) {
      int c = tc * 4 + j;
      float ts = 0, tq = 0;
      for (int g = 0; g < RG; ++g) { ts += rs[g][c]; tq += rq[g][c]; }
      atomicAdd(&sums[c], ts);
      atomicAdd(&sqs[c], tq);
    }
  }
}

__global__ void bn_finalize_k(const float* __restrict__ sums,
                              const float* __restrict__ sqs,
                              const float* __restrict__ gamma,
                              const float* __restrict__ beta,
                              float* __restrict__ af, float* __restrict__ bf,
                              int nc) {
  int c = threadIdx.x;
  if (c < nc) {
    float m = sums[c] * (1.0f / NN);
    float v = sqs[c] * (1.0f / NN) - m * m;
    float a = gamma[c] * rsqrtf(v + BNEPS);
    af[c] = a;
    bf[c] = beta[c] - m * a;
  }
}

// ---------------- MFMA GEMM ----------------
// C[M][NC] = pre(A) @ W, K=128, bf16 matrix cores, f32 accum.
// PRE: 0 = af[k]*v+bf[k] (f32 in) ; 1 = passthrough (bf16 in) ;
//      2 = relu(af[k]*(dinv[row]*v+preb[k])+bf[k]) (f32 in)
// EPI: 0 = relu(acc+bias[c]) -> bf16 ; 1 = acc*dinv[row] -> bf16
// A-tile staged in LDS bf16 [64][128] with XOR swizzle ^((r&7)<<4) (G4);
// B-fragments read from pre-transposed global Wt[n][128] bf16 (L1/L2-hot).
template <int NC, int PRE, int EPI>
__global__ __launch_bounds__(256) void mfma_gemm_k(
    const void* __restrict__ Ain, const unsigned short* __restrict__ Wt,
    const float* __restrict__ bias, const float* __restrict__ af,
    const float* __restrict__ bf, const float* __restrict__ preb,
    const float* __restrict__ dinv, unsigned short* __restrict__ O1) {
  constexpr int TM = 64;
  constexpr int NTILES = NC / 16;
  constexpr int CSTR = NC + 4;
  constexpr int ABYTES = TM * 128 * 2;       // 16 KB
  constexpr int CBYTES = TM * CSTR * 4;      // 33.8 KB (NC=128) / 17 KB (64)
  constexpr int SMEM =
      (PRE == 1) ? CBYTES : (ABYTES > CBYTES ? ABYTES : CBYTES);
  __shared__ __align__(16) char smem[SMEM];

  const int tid = threadIdx.x;
  const int row0 = blockIdx.x * TM;

  if constexpr (PRE != 1) {
    const float* A = (const float*)Ain;
    for (int f = tid; f < TM * 32; f += 256) {
      const int r = f >> 5;
      const int c4 = f & 31;
      const int rg = row0 + r;
      float4 v = make_float4(0.f, 0.f, 0.f, 0.f);
      if (rg < NN) {
        v = *(const float4*)&A[(size_t)rg * 128 + c4 * 4];
        if (PRE == 0) {
          const float4 a4 = *(const float4*)&af[c4 * 4];
          const float4 b4 = *(const float4*)&bf[c4 * 4];
          v.x = fmaf(a4.x, v.x, b4.x);
          v.y = fmaf(a4.y, v.y, b4.y);
          v.z = fmaf(a4.z, v.z, b4.z);
          v.w = fmaf(a4.w, v.w, b4.w);
        } else if (PRE == 2) {
          const float di = dinv[rg];
          const float4 a4 = *(const float4*)&af[c4 * 4];
          const float4 b4 = *(const float4*)&bf[c4 * 4];
          const float4 p4 = *(const float4*)&preb[c4 * 4];
          v.x = fmaxf(fmaf(a4.x, fmaf(di, v.x, p4.x), b4.x), 0.f);
          v.y = fmaxf(fmaf(a4.y, fmaf(di, v.y, p4.y), b4.y), 0.f);
          v.z = fmaxf(fmaf(a4.z, fmaf(di, v.z, p4.z), b4.z), 0.f);
          v.w = fmaxf(fmaf(a4.w, fmaf(di, v.w, p4.w), b4.w), 0.f);
        }
      }
      uint2 wv;
      wv.x = f2bf(v.x) | (f2bf(v.y) << 16);
      wv.y = f2bf(v.z) | (f2bf(v.w) << 16);
      const int ba = (r * 256 + c4 * 8) ^ ((r & 7) << 4);
      *(uint2*)(smem + ba) = wv;
    }
    __syncthreads();
  }

  // ---- MFMA main loop ----
  const int w = tid >> 6;
  const int l = tid & 63;
  const int lr = l & 15;
  const int lg = l >> 4;
  f32x4 acc[NTILES];
#pragma unroll
  for (int i = 0; i < NTILES; ++i) acc[i] = (f32x4){0.f, 0.f, 0.f, 0.f};
  const int arow = w * 16 + lr;
#pragma unroll
  for (int kt = 0; kt < 4; ++kt) {
    bf16x8 a;
    if constexpr (PRE == 1) {
      const unsigned short* Ab = (const unsigned short*)Ain;
      a = __builtin_bit_cast(
          bf16x8, *(const uint4*)&Ab[(size_t)(row0 + arow) * 128 + kt * 32 + lg * 8]);
    } else {
      const int ba = (arow * 256 + kt * 64 + lg * 16) ^ ((arow & 7) << 4);
      a = __builtin_bit_cast(bf16x8, *(const uint4*)(smem + ba));
    }
#pragma unroll
    for (int nt = 0; nt < NTILES; ++nt) {
      bf16x8 b = __builtin_bit_cast(
          bf16x8, *(const uint4*)&Wt[(size_t)(nt * 16 + lr) * 128 + kt * 32 + lg * 8]);
      acc[nt] = __builtin_amdgcn_mfma_f32_16x16x32_bf16(a, b, acc[nt], 0, 0, 0);
    }
  }
  __syncthreads();

  // ---- C repack via LDS (coalesced bf16 global stores) ----
  float* Cl = (float*)smem;
#pragma unroll
  for (int nt = 0; nt < NTILES; ++nt)
#pragma unroll
    for (int r = 0; r < 4; ++r)
      Cl[(w * 16 + lg * 4 + r) * CSTR + nt * 16 + lr] = acc[nt][r];
  __syncthreads();

  constexpr int CG = NC / 4;
  constexpr int RPT = TM * CG / 256;
  const int tc = tid % CG;
  const int tr = tid / CG;
  float4 b4 = make_float4(0.f, 0.f, 0.f, 0.f);
  if constexpr (EPI == 0) b4 = *(const float4*)&bias[tc * 4];
#pragma unroll
  for (int i = 0; i < RPT; ++i) {
    const int row = tr * RPT + i;
    const int rg = row0 + row;
    if (rg < NN) {
      float4 v = *(const float4*)&Cl[row * CSTR + tc * 4];
      if (EPI == 0) {
        v.x = fmaxf(v.x + b4.x, 0.f);
        v.y = fmaxf(v.y + b4.y, 0.f);
        v.z = fmaxf(v.z + b4.z, 0.f);
        v.w = fmaxf(v.w + b4.w, 0.f);
      } else {
        const float s = dinv[rg];
        v.x *= s; v.y *= s; v.z *= s; v.w *= s;
      }
      uint2 o;
      o.x = f2bf(v.x) | (f2bf(v.y) << 16);
      o.y = f2bf(v.z) | (f2bf(v.w) << 16);
      *(uint2*)&O1[(size_t)rg * NC + tc * 4] = o;
    }
  }
}

// ---------------- CSR gather aggregation (bf16 messages, f32 accum) ----
template <int NC>
__global__ __launch_bounds__(256) void gather_bf_k(
    const int* __restrict__ rowstart, const int* __restrict__ esrc,
    const unsigned short* __restrict__ Y, float* __restrict__ ACC) {
  constexpr int CG = NC / 8;
  constexpr int RG = 256 / CG;
  const int tc = threadIdx.x % CG;
  const int tr = threadIdx.x / CG;
  const int n = blockIdx.x * RG + tr;
  if (n >= NN) return;
  const int c = tc * 8;
  float a[8];
  {
    const uint4 p = *(const uint4*)&Y[(size_t)n * NC + c];
    a[0] = uplo(p.x); a[1] = uphi(p.x);
    a[2] = uplo(p.y); a[3] = uphi(p.y);
    a[4] = uplo(p.z); a[5] = uphi(p.z);
    a[6] = uplo(p.w); a[7] = uphi(p.w);
  }
  const int beg = rowstart[n];
  const int end = rowstart[n + 1];
  int e = beg;
  for (; e + 2 <= end; e += 2) {
    const int s0 = esrc[e];
    const int s1 = esrc[e + 1];
    const uint4 q0 = *(const uint4*)&Y[(size_t)s0 * NC + c];
    const uint4 q1 = *(const uint4*)&Y[(size_t)s1 * NC + c];
    a[0] += uplo(q0.x); a[1] += uphi(q0.x);
    a[2] += uplo(q0.y); a[3] += uphi(q0.y);
    a[4] += uplo(q0.z); a[5] += uphi(q0.z);
    a[6] += uplo(q0.w); a[7] += uphi(q0.w);
    a[0] += uplo(q1.x); a[1] += uphi(q1.x);
    a[2] += uplo(q1.y); a[3] += uphi(q1.y);
    a[4] += uplo(q1.z); a[5] += uphi(q1.z);
    a[6] += uplo(q1.w); a[7] += uphi(q1.w);
  }
  if (e < end) {
    const int s0 = esrc[e];
    const uint4 q0 = *(const uint4*)&Y[(size_t)s0 * NC + c];
    a[0] += uplo(q0.x); a[1] += uphi(q0.x);
    a[2] += uplo(q0.y); a[3] += uphi(q0.y);
    a[4] += uplo(q0.z); a[5] += uphi(q0.z);
    a[6] += uplo(q0.w); a[7] += uphi(q0.w);
  }
  float4 o0 = make_float4(a[0], a[1], a[2], a[3]);
  float4 o1 = make_float4(a[4], a[5], a[6], a[7]);
  *(float4*)&ACC[(size_t)n * NC + c] = o0;
  *(float4*)&ACC[(size_t)n * NC + c + 4] = o1;
}

// ---------------- final BN apply ----------------
__global__ __launch_bounds__(256) void final_k(const float* __restrict__ ACC2,
                                               const float* __restrict__ dinv,
                                               const float* __restrict__ cb,
                                               const float* __restrict__ af,
                                               const float* __restrict__ bf,
                                               float* __restrict__ out) {
  const int u = blockIdx.x * 256 + threadIdx.x;
  if (u >= NN * 16) return;
  const int r = u >> 4;
  const int c = (u & 15) * 4;
  const float di = dinv[r];
  float4 v = *(const float4*)&ACC2[(size_t)r * 64 + c];
  const float4 c4 = *(const float4*)&cb[c];
  const float4 a4 = *(const float4*)&af[c];
  const float4 b4 = *(const float4*)&bf[c];
  float4 o;
  o.x = fmaf(a4.x, fmaf(v.x, di, c4.x), b4.x);
  o.y = fmaf(a4.y, fmaf(v.y, di, c4.y), b4.y);
  o.z = fmaf(a4.z, fmaf(v.z, di, c4.z), b4.z);
  o.w = fmaf(a4.w, fmaf(v.w, di, c4.w), b4.w);
  *(float4*)&out[(size_t)r * 64 + c] = o;
}

extern "C" void kernel_launch(void* const* d_in, const int* in_sizes, int n_in,
                              void* d_out, int out_size, void* d_ws,
                              size_t ws_size, hipStream_t stream) {
  const float* x = (const float*)d_in[0];
  const int* ei = (const int*)d_in[1];
  const int* src = ei;
  const int* dst = ei + NE;
  const float* bn_in_g = (const float*)d_in[2];
  const float* bn_in_b = (const float*)d_in[3];
  const float* bn1_g = (const float*)d_in[4];
  const float* bn1_b = (const float*)d_in[5];
  const float* bn2_g = (const float*)d_in[6];
  const float* bn2_b = (const float*)d_in[7];
  const float* proj_W = (const float*)d_in[8];
  const float* proj_b = (const float*)d_in[9];
  const float* conv1_W = (const float*)d_in[10];
  const float* conv1_b = (const float*)d_in[11];
  const float* conv2_W = (const float*)d_in[12];
  const float* conv2_b = (const float*)d_in[13];
  float* out = (float*)d_out;

  float* ws = (float*)d_ws;
  float* dinv = ws + OFF_DINV;
  float* st = ws + OFF_ST;
  float* s0 = st;              float* q0 = st + 128;
  float* s1 = st + 256;        float* q1 = st + 384;
  float* s2 = st + 512;        float* q2 = st + 576;
  float* af0 = st + 640;       float* bf0 = st + 768;
  float* af1 = st + 896;       float* bf1 = st + 1024;
  float* af2 = st + 1152;      float* bf2 = st + 1216;
  int* deg = (int*)(ws + OFF_DEG);
  int* rowstart = (int*)(ws + OFF_ROWSTART);
  int* cursor = (int*)(ws + OFF_CURSOR);
  int* esrc = (int*)(ws + OFF_ESRC);
  int* bsum = (int*)(ws + OFF_BSUM);
  int* boff = (int*)(ws + OFF_BOFF);
  float* B0 = ws + OFF_B0;
  float* B1 = ws + OFF_B1;
  unsigned short* Wt0 = (unsigned short*)(ws + OFF_WT0);  // proj  [128][128]
  unsigned short* Wt1 = (unsigned short*)(ws + OFF_WT1);  // conv1 [128][128]
  unsigned short* Wt2 = (unsigned short*)(ws + OFF_WT2);  // conv2 [64][128]
  // sequential aliasing: each buffer generation fully written before read
  unsigned short* H1bf = (unsigned short*)B0;  // gemm1 out (bf16), conv1 in
  unsigned short* Ybf = (unsigned short*)B1;   // conv1 out (bf16), gather1 in
  float* ACC = B0;                             // gather1 out (H1 dead)
  unsigned short* Y2bf = (unsigned short*)B1;  // conv2 out (Y dead)
  float* ACC2 = B0;                            // gather2 out (ACC dead)

  const int nb_n = (NN + 255) / 256;
  wtrans3_k<<<160, 256, 0, stream>>>(proj_W, conv1_W, conv2_W, Wt0, Wt1, Wt2);
  init_k<<<nb_n, 256, 0, stream>>>(deg, st);
  deg_k<<<(NE + 255) / 256, 256, 0, stream>>>(dst, deg);
  block_sum_k<<<NBLK, SB, 0, stream>>>(deg, bsum);
  bscan_k<<<1, 128, 0, stream>>>(bsum, boff);
  scan_fin_k<<<NBLK, SB, 0, stream>>>(deg, boff, rowstart, cursor, dinv);
  fill_k<<<(NE + 255) / 256, 256, 0, stream>>>(src, dst, cursor, esrc);

  // layer 0: BN(x) folded into GEMM1 staging
  bn_stats_k<128, 0><<<256, 256, 0, stream>>>(x, nullptr, nullptr, s0, q0);
  bn_finalize_k<<<1, 128, 0, stream>>>(s0, q0, bn_in_g, bn_in_b, af0, bf0, 128);

  const int nt64 = (NN + 63) / 64;  // 782 row tiles
  // H1bf = bf16(relu(BN(x) @ proj_W + proj_b))
  mfma_gemm_k<128, 0, 0><<<nt64, 256, 0, stream>>>(
      x, Wt0, proj_b, af0, bf0, nullptr, dinv, H1bf);
  // conv1: Ybf = bf16((H1 @ conv1_W) * dinv[row])
  mfma_gemm_k<128, 1, 1><<<nt64, 256, 0, stream>>>(
      H1bf, Wt1, nullptr, nullptr, nullptr, nullptr, dinv, Ybf);
  gather_bf_k<128><<<(NN + 15) / 16, 256, 0, stream>>>(rowstart, esrc, Ybf, ACC);
  // BN1 stats on z1 = dinv[r]*ACC + conv1_b
  bn_stats_k<128, 1><<<256, 256, 0, stream>>>(ACC, dinv, conv1_b, s1, q1);
  bn_finalize_k<<<1, 128, 0, stream>>>(s1, q1, bn1_g, bn1_b, af1, bf1, 128);
  // conv2: input = relu(BN1(z1)) computed in staging; bf16 out
  mfma_gemm_k<64, 2, 1><<<nt64, 256, 0, stream>>>(
      ACC, Wt2, nullptr, af1, bf1, conv1_b, dinv, Y2bf);
  gather_bf_k<64><<<(NN + 31) / 32, 256, 0, stream>>>(rowstart, esrc, Y2bf, ACC2);
  // BN2 stats on z2 = dinv[r]*ACC2 + conv2_b
  bn_stats_k<64, 1><<<256, 256, 0, stream>>>(ACC2, dinv, conv2_b, s2, q2);
  bn_finalize_k<<<1, 128, 0, stream>>>(s2, q2, bn2_g, bn2_b, af2, bf2, 64);
  final_k<<<(NN * 16 + 255) / 256, 256, 0, stream>>>(ACC2, dinv, conv2_b, af2,
                                                     bf2, out);
}